// Round 1
// baseline (7349.289 us; speedup 1.0000x reference)
//
#include <hip/hip_runtime.h>
#include <math.h>

#define N_NODES 65536
#define HW      65536
#define NE      524288
#define NC      (N_NODES * 64)

// ---------------- CSR build ----------------
__global__ void k_hist(const int* __restrict__ dstA, int* __restrict__ cnt) {
    int e = blockIdx.x * 256 + threadIdx.x;
    if (e < NE) atomicAdd(&cnt[dstA[e]], 1);
}

__global__ void k_scan(const int* __restrict__ cnt, int* __restrict__ off) {
    __shared__ int sums[1024];
    int t = threadIdx.x;
    int base = t * 64;
    int s = 0;
    for (int i = 0; i < 64; ++i) s += cnt[base + i];
    sums[t] = s;
    __syncthreads();
    for (int d = 1; d < 1024; d <<= 1) {
        int v = (t >= d) ? sums[t - d] : 0;
        __syncthreads();
        sums[t] += v;
        __syncthreads();
    }
    int run = sums[t] - s;  // exclusive prefix
    for (int i = 0; i < 64; ++i) { off[base + i] = run; run += cnt[base + i]; }
    if (t == 1023) off[N_NODES] = run;
}

__global__ void k_fill(const int* __restrict__ srcA, const int* __restrict__ dstA,
                       int* __restrict__ cur, int* __restrict__ csr) {
    int e = blockIdx.x * 256 + threadIdx.x;
    if (e < NE) {
        int p = atomicAdd(&cur[dstA[e]], 1);
        csr[p] = srcA[e];
    }
}

// ---------------- weight re-layout ----------------
// rb_w [16][co=64][ci=64][3][3]  ->  wt [16][ci][tap=9][co]
__global__ void k_wtrans(const float* __restrict__ w, float* __restrict__ wt) {
    int idx = blockIdx.x * 256 + threadIdx.x;
    if (idx >= 16 * 64 * 9 * 64) return;
    int co  = idx & 63;
    int tap = (idx >> 6) % 9;
    int ci  = (idx / (9 * 64)) % 64;
    int cv  = idx / (64 * 9 * 64);
    wt[idx] = w[((cv * 64 + co) * 64 + ci) * 9 + tap];
}

// cc_w [3][o=64][k=192] -> cct [3][k=192][o=64]
__global__ void k_cctrans(const float* __restrict__ w, float* __restrict__ wt) {
    int idx = blockIdx.x * 256 + threadIdx.x;
    if (idx >= 3 * 192 * 64) return;
    int o  = idx & 63;
    int k  = (idx >> 6) % 192;
    int ci = idx / (192 * 64);
    wt[idx] = w[ci * 64 * 192 + o * 192 + k];
}

// ---------------- image [64][HW] -> nodes [HW][64] ----------------
__global__ void k_img2nodes(const float* __restrict__ img, float* __restrict__ xn) {
    __shared__ float tile[64][65];
    int nb = blockIdx.x * 64;
    for (int idx = threadIdx.x; idx < 4096; idx += 256) {
        int c = idx >> 6, n = idx & 63;
        tile[c][n] = img[c * HW + nb + n];
    }
    __syncthreads();
    for (int idx = threadIdx.x; idx < 4096; idx += 256) {
        int n = idx >> 6, c = idx & 63;
        xn[(nb + n) * 64 + c] = tile[c][n];
    }
}

// ---------------- dual matmul: XL = X@Wl, XR = X@Wr ----------------
__global__ __launch_bounds__(256) void k_dualmm(const float* __restrict__ X,
        const float* __restrict__ Wl, const float* __restrict__ Wr,
        float* __restrict__ XL, float* __restrict__ XR) {
    __shared__ float xs[128][65];
    int t = threadIdx.x;
    int n0 = blockIdx.x * 128;
    for (int idx = t; idx < 128 * 64; idx += 256) {
        int r = idx >> 6, k = idx & 63;
        xs[r][k] = X[(n0 + r) * 64 + k];
    }
    __syncthreads();
    int wave = t >> 6, lane = t & 63;
    int half = wave >> 1;
    int rowb = (wave & 1) << 6;
    int row  = rowb + lane;
    int hs = __builtin_amdgcn_readfirstlane(half) * 32;
    const float* wl = Wl + hs;
    const float* wr = Wr + hs;
    float accl[32], accr[32];
#pragma unroll
    for (int j = 0; j < 32; ++j) { accl[j] = 0.f; accr[j] = 0.f; }
    for (int k = 0; k < 64; ++k) {
        float xv = xs[row][k];
#pragma unroll
        for (int j = 0; j < 32; ++j) accl[j] += xv * wl[k * 64 + j];
#pragma unroll
        for (int j = 0; j < 32; ++j) accr[j] += xv * wr[k * 64 + j];
    }
    int node = n0 + row;
#pragma unroll
    for (int j = 0; j < 32; ++j) XL[node * 64 + hs + j] = accl[j];
#pragma unroll
    for (int j = 0; j < 32; ++j) XR[node * 64 + hs + j] = accr[j];
}

// ---------------- GAT edge phase: online softmax + aggregate + bias + ELU ----------------
__global__ __launch_bounds__(256) void k_gat(const float* __restrict__ XL,
        const float* __restrict__ XR, const float* __restrict__ att64,
        const float* __restrict__ bias, const int* __restrict__ off,
        const int* __restrict__ csr, float* __restrict__ out) {
    int lane = threadIdx.x & 63;
    int node = (blockIdx.x << 2) + (threadIdx.x >> 6);
    float xi = XR[node * 64 + lane];
    float a  = att64[lane];
    float b  = bias[lane];
    int e0 = off[node], e1 = off[node + 1];
    float m = -INFINITY, s = 0.f, acc = 0.f;
    for (int e = e0; e < e1; ++e) {
        int src = csr[e];
        float xj = XL[src * 64 + lane];
        float v = xi + xj;
        v = v > 0.f ? v : 0.2f * v;
        float p = v * a;
        p += __shfl_xor(p, 1);
        p += __shfl_xor(p, 2);
        p += __shfl_xor(p, 4);
        p += __shfl_xor(p, 8);        // all 16 lanes of the head now hold the logit
        float mn = fmaxf(m, p);
        float sc = __expf(m - mn);    // exp(-inf)=0 on first edge
        float ex = __expf(p - mn);
        s   = s * sc + ex;
        acc = acc * sc + ex * xj;
        m = mn;
    }
    float val = acc / (s + 1e-16f) + b;
    out[node * 64 + lane] = val > 0.f ? val : __expf(val) - 1.f;  // ELU
}

// ---------------- 1x1 conv over 3 concatenated branches + bias + residual ----------------
__global__ __launch_bounds__(256) void k_cc(const float* __restrict__ b0,
        const float* __restrict__ b1, const float* __restrict__ b2,
        const float* __restrict__ Wt /*[192][64]*/, const float* __restrict__ bias,
        const float* __restrict__ resin /*[64][HW]*/, float* __restrict__ outimg) {
    __shared__ float xs[128][65];
    int t = threadIdx.x;
    int n0 = blockIdx.x * 128;
    int wave = t >> 6, lane = t & 63;
    int half = wave >> 1;
    int rowb = (wave & 1) << 6;
    int row  = rowb + lane;
    int hs = __builtin_amdgcn_readfirstlane(half) * 32;
    float acc[32];
#pragma unroll
    for (int j = 0; j < 32; ++j) acc[j] = 0.f;
    const float* brs[3] = {b0, b1, b2};
#pragma unroll
    for (int br = 0; br < 3; ++br) {
        __syncthreads();
        const float* B = brs[br];
        for (int idx = t; idx < 8192; idx += 256) {
            int r = idx >> 6, k = idx & 63;
            xs[r][k] = B[(n0 + r) * 64 + k];
        }
        __syncthreads();
        const float* w = Wt + (br * 64) * 64 + hs;
        for (int k = 0; k < 64; ++k) {
            float xv = xs[row][k];
#pragma unroll
            for (int j = 0; j < 32; ++j) acc[j] += xv * w[k * 64 + j];
        }
    }
    int node = n0 + row;
#pragma unroll
    for (int j = 0; j < 32; ++j) {
        int o = hs + j;
        outimg[o * HW + node] = acc[j] + bias[o] + resin[o * HW + node];
    }
}

// ---------------- 3x3 conv 64->64, NCHW, SAME ----------------
// MODE 0: out = prelu(conv(in)+b);  MODE 1: out = conv(in)+b+res (in-place-safe on res)
template <int MODE>
__global__ __launch_bounds__(256) void k_conv3(const float* __restrict__ in,
        const float* __restrict__ wt /*[ci][9][co]*/, const float* __restrict__ bias,
        const float* __restrict__ prelu_a, const float* __restrict__ res,
        float* __restrict__ out) {
    __shared__ float tile[18 * 18];
    int t = threadIdx.x;
    int bx = blockIdx.x & 15, by = blockIdx.x >> 4;
    int px = t & 15, py = t >> 4;
    float acc[64];
#pragma unroll
    for (int co = 0; co < 64; ++co) acc[co] = 0.f;
    for (int ci = 0; ci < 64; ++ci) {
        __syncthreads();
        for (int idx = t; idx < 324; idx += 256) {
            int ty = idx / 18, tx = idx % 18;
            int sy = by * 16 + ty - 1, sx = bx * 16 + tx - 1;
            float v = 0.f;
            if (sy >= 0 && sy < 256 && sx >= 0 && sx < 256)
                v = in[ci * HW + sy * 256 + sx];
            tile[idx] = v;
        }
        __syncthreads();
        float rv[9];
#pragma unroll
        for (int dy = 0; dy < 3; ++dy)
#pragma unroll
            for (int dx = 0; dx < 3; ++dx)
                rv[dy * 3 + dx] = tile[(py + dy) * 18 + px + dx];
        const float* wci = wt + ci * 9 * 64;
#pragma unroll
        for (int tap = 0; tap < 9; ++tap) {
            float v = rv[tap];
#pragma unroll
            for (int co = 0; co < 64; ++co) acc[co] += v * wci[tap * 64 + co];
        }
    }
    int pix = (by * 16 + py) * 256 + bx * 16 + px;
    if (MODE == 0) {
        float a = prelu_a[0];
#pragma unroll
        for (int co = 0; co < 64; ++co) {
            float v = acc[co] + bias[co];
            out[co * HW + pix] = v >= 0.f ? v : a * v;
        }
    } else {
#pragma unroll
        for (int co = 0; co < 64; ++co) {
            out[co * HW + pix] = acc[co] + bias[co] + res[co * HW + pix];
        }
    }
}

// ---------------- host ----------------
extern "C" void kernel_launch(void* const* d_in, const int* in_sizes, int n_in,
                              void* d_out, int out_size, void* d_ws, size_t ws_size,
                              hipStream_t stream) {
    const float* x    = (const float*)d_in[0];
    const int*   ei   = (const int*)d_in[1];
    const float* gWl  = (const float*)d_in[2];   // [9][3][64][64]
    const float* gWr  = (const float*)d_in[3];
    const float* gatt = (const float*)d_in[4];   // [9][3][64]
    const float* gb   = (const float*)d_in[5];   // [9][3][64]
    const float* ccw  = (const float*)d_in[6];   // [3][64][192]
    const float* ccb  = (const float*)d_in[7];   // [3][64]
    const float* rbw  = (const float*)d_in[8];   // [2][4][2][64][64][3][3]
    const float* rbb  = (const float*)d_in[9];   // [2][4][2][64]
    const float* rba  = (const float*)d_in[10];  // [2][4]
    float* outp = (float*)d_out;

    float* wsf = (float*)d_ws;
    float* xn  = wsf;
    float* t0  = xn  + NC;
    float* br0 = t0  + NC;
    float* br1 = br0 + NC;
    float* br2 = br1 + NC;
    float* xl  = br2 + NC;
    float* xr  = xl  + NC;
    float* img = xr  + NC;
    float* wt  = img + NC;            // 16*64*9*64 = 589824
    float* cct = wt  + 589824;        // 3*192*64  = 36864
    int* ioff = (int*)(cct + 36864);  // N+1
    int* icnt = ioff + (N_NODES + 1);
    int* icur = icnt + N_NODES;
    int* icsr = icur + N_NODES;       // NE

    const int* srcA = ei;
    const int* dstA = ei + NE;

    hipMemsetAsync(icnt, 0, N_NODES * sizeof(int), stream);
    k_hist<<<NE / 256, 256, 0, stream>>>(dstA, icnt);
    k_scan<<<1, 1024, 0, stream>>>(icnt, ioff);
    hipMemcpyAsync(icur, ioff, N_NODES * sizeof(int), hipMemcpyDeviceToDevice, stream);
    k_fill<<<NE / 256, 256, 0, stream>>>(srcA, dstA, icur, icsr);
    k_wtrans<<<(16 * 64 * 9 * 64) / 256, 256, 0, stream>>>(rbw, wt);
    k_cctrans<<<(3 * 192 * 64) / 256, 256, 0, stream>>>(ccw, cct);

    const float* cur_img = x;
    float* brs[3] = {br0, br1, br2};
    for (int st = 0; st < 3; ++st) {
        k_img2nodes<<<1024, 256, 0, stream>>>(cur_img, xn);
        for (int mb = 0; mb < 3; ++mb) {
            int m = st * 3 + mb;
            const float* lin = xn;
            for (int l = 0; l < 3; ++l) {
                const float* Wl = gWl + (m * 3 + l) * 4096;
                const float* Wr = gWr + (m * 3 + l) * 4096;
                const float* at = gatt + (m * 3 + l) * 64;
                const float* bb = gb + (m * 3 + l) * 64;
                float* lout = (l == 2) ? brs[mb] : t0;
                k_dualmm<<<N_NODES / 128, 256, 0, stream>>>(lin, Wl, Wr, xl, xr);
                k_gat<<<N_NODES / 4, 256, 0, stream>>>(xl, xr, at, bb, ioff, icsr, lout);
                lin = lout;
            }
        }
        float* stage_out = (st == 2) ? outp : img;
        k_cc<<<N_NODES / 128, 256, 0, stream>>>(br0, br1, br2, cct + st * 192 * 64,
                                                ccb + st * 64, cur_img, stage_out);
        if (st < 2) {
            for (int bk = 0; bk < 4; ++bk) {
                int cv = (st * 4 + bk) * 2;
                const float* w1 = wt + (size_t)(cv + 0) * 64 * 9 * 64;
                const float* w2 = wt + (size_t)(cv + 1) * 64 * 9 * 64;
                const float* b1 = rbb + (cv + 0) * 64;
                const float* b2 = rbb + (cv + 1) * 64;
                const float* av = rba + st * 4 + bk;
                k_conv3<0><<<256, 256, 0, stream>>>(img, w1, b1, av, nullptr, t0);
                k_conv3<1><<<256, 256, 0, stream>>>(t0, w2, b2, nullptr, img, img);
            }
            cur_img = img;
        }
    }
}

// Round 2
// 2734.929 us; speedup vs baseline: 2.6872x; 2.6872x over previous
//
#include <hip/hip_runtime.h>
#include <hip/hip_bf16.h>
#include <math.h>

#define N_NODES 65536
#define HW      65536
#define NE      524288
#define NC      (N_NODES * 64)

typedef __bf16 bf16x8 __attribute__((ext_vector_type(8)));
typedef float  f32x4  __attribute__((ext_vector_type(4)));
typedef int    i32x4  __attribute__((ext_vector_type(4)));

static __device__ __forceinline__ f32x4 mfma16(bf16x8 a, bf16x8 b, f32x4 c) {
    return __builtin_amdgcn_mfma_f32_16x16x32_bf16(a, b, c, 0, 0, 0);
}

// ---------------- CSR build ----------------
__global__ void k_hist(const int* __restrict__ dstA, int* __restrict__ cnt) {
    int e = blockIdx.x * 256 + threadIdx.x;
    if (e < NE) atomicAdd(&cnt[dstA[e]], 1);
}

__global__ void k_scan(const int* __restrict__ cnt, int* __restrict__ off) {
    __shared__ int sums[1024];
    int t = threadIdx.x;
    int base = t * 64;
    int s = 0;
    for (int i = 0; i < 64; ++i) s += cnt[base + i];
    sums[t] = s;
    __syncthreads();
    for (int d = 1; d < 1024; d <<= 1) {
        int v = (t >= d) ? sums[t - d] : 0;
        __syncthreads();
        sums[t] += v;
        __syncthreads();
    }
    int run = sums[t] - s;  // exclusive prefix
    for (int i = 0; i < 64; ++i) { off[base + i] = run; run += cnt[base + i]; }
    if (t == 1023) off[N_NODES] = run;
}

__global__ void k_fill(const int* __restrict__ srcA, const int* __restrict__ dstA,
                       int* __restrict__ cur, int* __restrict__ csr) {
    int e = blockIdx.x * 256 + threadIdx.x;
    if (e < NE) {
        int p = atomicAdd(&cur[dstA[e]], 1);
        csr[p] = srcA[e];
    }
}

// ---------------- weight packing (MFMA fragment order) ----------------
// conv: rb_w [16][co][ci][3][3] -> [cv][tap][nt][kk][lane][8] bf16
__global__ void k_cvpack(const float* __restrict__ w, __hip_bfloat16* __restrict__ d) {
    int idx = blockIdx.x * 256 + threadIdx.x;
    if (idx >= 589824) return;
    int j = idx & 7, lane = (idx >> 3) & 63, r = idx >> 9;
    int kk = r & 1; r >>= 1;
    int nt = r & 3; r >>= 2;
    int tap = r % 9, cv = r / 9;
    int co = nt * 16 + (lane & 15);
    int ci = kk * 32 + (lane >> 4) * 8 + j;
    d[idx] = __float2bfloat16(w[((cv * 64 + co) * 64 + ci) * 9 + tap]);
}

// gat mm: gWl/gWr [27][ci][co] -> [lay][side][nt][kk][lane][8] bf16
__global__ void k_mmpack(const float* __restrict__ Wl, const float* __restrict__ Wr,
                         __hip_bfloat16* __restrict__ d) {
    int idx = blockIdx.x * 256 + threadIdx.x;
    if (idx >= 221184) return;
    int j = idx & 7, lane = (idx >> 3) & 63, r = idx >> 9;
    int kk = r & 1; r >>= 1;
    int nt = r & 3; r >>= 2;
    int side = r & 1, lay = r >> 1;
    int co = nt * 16 + (lane & 15);
    int ci = kk * 32 + (lane >> 4) * 8 + j;
    const float* W = side ? Wr : Wl;
    d[idx] = __float2bfloat16(W[lay * 4096 + ci * 64 + co]);
}

// cc_w [3][o=64][k=192] -> cct [3][k=192][o=64]  (fp32)
__global__ void k_cctrans(const float* __restrict__ w, float* __restrict__ wt) {
    int idx = blockIdx.x * 256 + threadIdx.x;
    if (idx >= 3 * 192 * 64) return;
    int o  = idx & 63;
    int k  = (idx >> 6) % 192;
    int ci = idx / (192 * 64);
    wt[idx] = w[ci * 64 * 192 + o * 192 + k];
}

// ---------------- initial NCHW -> [N,64] fp32 + bf16 ----------------
__global__ void k_init(const float* __restrict__ img, float* __restrict__ xn,
                       __hip_bfloat16* __restrict__ xb) {
    __shared__ float tile[64][65];
    int nb = blockIdx.x * 64;
    for (int idx = threadIdx.x; idx < 4096; idx += 256) {
        int c = idx >> 6, n = idx & 63;
        tile[c][n] = img[c * HW + nb + n];
    }
    __syncthreads();
    for (int idx = threadIdx.x; idx < 4096; idx += 256) {
        int n = idx >> 6, c = idx & 63;
        float v = tile[c][n];
        xn[(nb + n) * 64 + c] = v;
        xb[(nb + n) * 64 + c] = __float2bfloat16(v);
    }
}

// ---------------- MFMA dual matmul: XL = X@Wl, XR = X@Wr ----------------
__global__ __launch_bounds__(256) void k_mm(const __hip_bfloat16* __restrict__ Xb,
        const __hip_bfloat16* __restrict__ pw, float* __restrict__ XL,
        float* __restrict__ XR) {
    __shared__ i32x4 la[128 * 8];
    int t = threadIdx.x, lane = t & 63, wid = t >> 6;
    int n0 = blockIdx.x * 128;
    const i32x4* Xg = (const i32x4*)Xb + n0 * 8;
    for (int idx = t; idx < 1024; idx += 256) {
        int r = idx >> 3, c = idx & 7;
        la[r * 8 + (c ^ (r & 7))] = Xg[idx];
    }
    int side = wid & 1, rh = wid >> 1;
    const i32x4* wpt = (const i32x4*)pw + side * 512 + lane;
    f32x4 acc[4][4];
#pragma unroll
    for (int mi = 0; mi < 4; ++mi)
#pragma unroll
        for (int nt = 0; nt < 4; ++nt) acc[mi][nt] = (f32x4)0.0f;
    bf16x8 b[4][2];
#pragma unroll
    for (int nt = 0; nt < 4; ++nt)
#pragma unroll
        for (int kk = 0; kk < 2; ++kk)
            b[nt][kk] = __builtin_bit_cast(bf16x8, wpt[(nt * 2 + kk) * 64]);
    __syncthreads();
#pragma unroll
    for (int mi = 0; mi < 4; ++mi) {
        int row = rh * 64 + mi * 16 + (lane & 15);
#pragma unroll
        for (int kk = 0; kk < 2; ++kk) {
            bf16x8 a = __builtin_bit_cast(bf16x8,
                la[row * 8 + (((kk << 2) | (lane >> 4)) ^ (row & 7))]);
#pragma unroll
            for (int nt = 0; nt < 4; ++nt)
                acc[mi][nt] = mfma16(a, b[nt][kk], acc[mi][nt]);
        }
    }
    float* O = side ? XR : XL;
#pragma unroll
    for (int mi = 0; mi < 4; ++mi)
#pragma unroll
        for (int nt = 0; nt < 4; ++nt) {
            int co = nt * 16 + (lane & 15);
#pragma unroll
            for (int r = 0; r < 4; ++r)
                O[(n0 + rh * 64 + mi * 16 + (lane >> 4) * 4 + r) * 64 + co] =
                    acc[mi][nt][r];
        }
}

// ---------------- GAT edge phase ----------------
template <int WF32, int WB16>
__global__ __launch_bounds__(256) void k_gat(const float* __restrict__ XL,
        const float* __restrict__ XR, const float* __restrict__ att64,
        const float* __restrict__ bias, const int* __restrict__ off,
        const int* __restrict__ csr, float* __restrict__ outf,
        __hip_bfloat16* __restrict__ outb) {
    int lane = threadIdx.x & 63;
    int node = (blockIdx.x << 2) + (threadIdx.x >> 6);
    float xi = XR[node * 64 + lane];
    float a  = att64[lane];
    float b  = bias[lane];
    int e0 = off[node], e1 = off[node + 1];
    float m = -INFINITY, s = 0.f, acc = 0.f;
    for (int e = e0; e < e1; ++e) {
        int src = csr[e];
        float xj = XL[src * 64 + lane];
        float v = xi + xj;
        v = v > 0.f ? v : 0.2f * v;
        float p = v * a;
        p += __shfl_xor(p, 1);
        p += __shfl_xor(p, 2);
        p += __shfl_xor(p, 4);
        p += __shfl_xor(p, 8);
        float mn = fmaxf(m, p);
        float sc = __expf(m - mn);
        float ex = __expf(p - mn);
        s   = s * sc + ex;
        acc = acc * sc + ex * xj;
        m = mn;
    }
    float val = acc / (s + 1e-16f) + b;
    val = val > 0.f ? val : __expf(val) - 1.f;  // ELU
    if constexpr (WF32) outf[node * 64 + lane] = val;
    if constexpr (WB16) outb[node * 64 + lane] = __float2bfloat16(val);
}

// ---------------- 1x1 conv over 3 branches + bias + residual ----------------
template <int FINAL>
__global__ __launch_bounds__(256) void k_cc(const float* __restrict__ b0,
        const float* __restrict__ b1, const float* __restrict__ b2,
        const float* __restrict__ Wt /*[192][64]*/, const float* __restrict__ bias,
        const float* __restrict__ resin /*[N,64]*/, float* __restrict__ outf,
        __hip_bfloat16* __restrict__ outb) {
    __shared__ float xs[128][65];
    int t = threadIdx.x;
    int n0 = blockIdx.x * 128;
    int wave = t >> 6, lane = t & 63;
    int half = wave >> 1;
    int row  = ((wave & 1) << 6) + lane;
    int hs = __builtin_amdgcn_readfirstlane(half) * 32;
    float acc[32];
#pragma unroll
    for (int j = 0; j < 32; ++j) acc[j] = 0.f;
    const float* brs[3] = {b0, b1, b2};
#pragma unroll
    for (int br = 0; br < 3; ++br) {
        __syncthreads();
        const float* B = brs[br];
        for (int idx = t; idx < 8192; idx += 256) {
            int r = idx >> 6, k = idx & 63;
            xs[r][k] = B[(n0 + r) * 64 + k];
        }
        __syncthreads();
        const float* w = Wt + (br * 64) * 64 + hs;
        for (int k = 0; k < 64; ++k) {
            float xv = xs[row][k];
#pragma unroll
            for (int j = 0; j < 32; ++j) acc[j] += xv * w[k * 64 + j];
        }
    }
    int node = n0 + row;
#pragma unroll
    for (int j = 0; j < 32; ++j) {
        int o = hs + j;
        float v = acc[j] + bias[o] + resin[node * 64 + o];
        if (FINAL) {
            outf[o * HW + node] = v;   // NCHW final output
        } else {
            outf[node * 64 + o] = v;
            outb[node * 64 + o] = __float2bfloat16(v);
        }
    }
}

// ---------------- 3x3 conv 64->64, channels-last, MFMA ----------------
// MODE 0: outb = bf16(prelu(conv+b));  MODE 1: img += conv+b (fp32), outb = bf16(img)
template <int MODE>
__global__ __launch_bounds__(256) void k_conv(const __hip_bfloat16* __restrict__ inb,
        const __hip_bfloat16* __restrict__ wp, const float* __restrict__ bias,
        const float* __restrict__ pa, float* __restrict__ img,
        __hip_bfloat16* __restrict__ outb) {
    __shared__ i32x4 la[130 * 8];
    int t = threadIdx.x, lane = t & 63, wid = t >> 6;
    int y = blockIdx.x >> 1, x0 = (blockIdx.x & 1) << 7;
    f32x4 acc[2][4];
#pragma unroll
    for (int mi = 0; mi < 2; ++mi)
#pragma unroll
        for (int nt = 0; nt < 4; ++nt) acc[mi][nt] = (f32x4)0.0f;
    const i32x4* ing = (const i32x4*)inb;
#pragma unroll
    for (int dy = 0; dy < 3; ++dy) {
        int sy = y + dy - 1;
        bool rowok = (sy >= 0) && (sy < 256);
        __syncthreads();
        for (int idx = t; idx < 1040; idx += 256) {
            int r = idx >> 3, c = idx & 7;
            int sx = x0 - 1 + r;
            i32x4 v = (i32x4)0;
            if (rowok && sx >= 0 && sx < 256) v = ing[(sy * 256 + sx) * 8 + c];
            la[r * 8 + (c ^ (r & 7))] = v;
        }
        __syncthreads();
#pragma unroll
        for (int dx = 0; dx < 3; ++dx) {
            const i32x4* wpt = (const i32x4*)wp + (dy * 3 + dx) * 512 + lane;
            bf16x8 b[4][2];
#pragma unroll
            for (int nt = 0; nt < 4; ++nt)
#pragma unroll
                for (int kk = 0; kk < 2; ++kk)
                    b[nt][kk] = __builtin_bit_cast(bf16x8, wpt[(nt * 2 + kk) * 64]);
#pragma unroll
            for (int mi = 0; mi < 2; ++mi) {
                int row = dx + wid * 32 + mi * 16 + (lane & 15);
#pragma unroll
                for (int kk = 0; kk < 2; ++kk) {
                    bf16x8 a = __builtin_bit_cast(bf16x8,
                        la[row * 8 + (((kk << 2) | (lane >> 4)) ^ (row & 7))]);
#pragma unroll
                    for (int nt = 0; nt < 4; ++nt)
                        acc[mi][nt] = mfma16(a, b[nt][kk], acc[mi][nt]);
                }
            }
        }
    }
    int pbase = y * 256 + x0 + wid * 32 + (lane >> 4) * 4;
    float aprelu = (MODE == 0) ? pa[0] : 0.f;
#pragma unroll
    for (int mi = 0; mi < 2; ++mi)
#pragma unroll
        for (int nt = 0; nt < 4; ++nt) {
            int co = nt * 16 + (lane & 15);
            float bv = bias[co];
#pragma unroll
            for (int r = 0; r < 4; ++r) {
                int pix = pbase + mi * 16 + r;
                float v = acc[mi][nt][r] + bv;
                if (MODE == 0) {
                    v = v >= 0.f ? v : aprelu * v;
                    outb[pix * 64 + co] = __float2bfloat16(v);
                } else {
                    v += img[pix * 64 + co];
                    img[pix * 64 + co] = v;
                    outb[pix * 64 + co] = __float2bfloat16(v);
                }
            }
        }
}

// ---------------- host ----------------
extern "C" void kernel_launch(void* const* d_in, const int* in_sizes, int n_in,
                              void* d_out, int out_size, void* d_ws, size_t ws_size,
                              hipStream_t stream) {
    const float* x    = (const float*)d_in[0];
    const int*   ei   = (const int*)d_in[1];
    const float* gWl  = (const float*)d_in[2];   // [27][64][64]
    const float* gWr  = (const float*)d_in[3];
    const float* gatt = (const float*)d_in[4];   // [27][64]
    const float* gb   = (const float*)d_in[5];   // [27][64]
    const float* ccw  = (const float*)d_in[6];   // [3][64][192]
    const float* ccb  = (const float*)d_in[7];   // [3][64]
    const float* rbw  = (const float*)d_in[8];   // [16][64][64][3][3]
    const float* rbb  = (const float*)d_in[9];   // [16][64]
    const float* rba  = (const float*)d_in[10];  // [8]
    float* outp = (float*)d_out;

    float* wsf = (float*)d_ws;
    float* xn  = wsf;            // [N,64] fp32 stage-0 residual
    float* br0 = xn  + NC;
    float* br1 = br0 + NC;
    float* br2 = br1 + NC;
    float* xl  = br2 + NC;
    float* xr  = xl  + NC;
    float* img = xr  + NC;       // [N,64] fp32 running image
    float* cct = img + NC;       // 36864
    __hip_bfloat16* xb   = (__hip_bfloat16*)(cct + 36864);  // NC bf16
    __hip_bfloat16* t0b  = xb  + NC;
    __hip_bfloat16* cvb  = t0b + NC;
    __hip_bfloat16* wpkc = cvb + NC;        // 589824
    __hip_bfloat16* wpkm = wpkc + 589824;   // 221184
    int* ioff = (int*)(wpkm + 221184);
    int* icnt = ioff + (N_NODES + 1);
    int* icur = icnt + N_NODES;
    int* icsr = icur + N_NODES;             // NE

    const int* srcA = ei;
    const int* dstA = ei + NE;

    hipMemsetAsync(icnt, 0, N_NODES * sizeof(int), stream);
    k_hist<<<NE / 256, 256, 0, stream>>>(dstA, icnt);
    k_scan<<<1, 1024, 0, stream>>>(icnt, ioff);
    hipMemcpyAsync(icur, ioff, N_NODES * sizeof(int), hipMemcpyDeviceToDevice, stream);
    k_fill<<<NE / 256, 256, 0, stream>>>(srcA, dstA, icur, icsr);
    k_cvpack<<<2304, 256, 0, stream>>>(rbw, wpkc);
    k_mmpack<<<864, 256, 0, stream>>>(gWl, gWr, wpkm);
    k_cctrans<<<144, 256, 0, stream>>>(ccw, cct);
    k_init<<<1024, 256, 0, stream>>>(x, xn, xb);

    float* brs[3] = {br0, br1, br2};
    for (int st = 0; st < 3; ++st) {
        for (int mb = 0; mb < 3; ++mb) {
            const __hip_bfloat16* lin = xb;
            for (int l = 0; l < 3; ++l) {
                int lay = (st * 3 + mb) * 3 + l;
                k_mm<<<N_NODES / 128, 256, 0, stream>>>(lin, wpkm + lay * 8192, xl, xr);
                const float* at = gatt + lay * 64;
                const float* bb = gb + lay * 64;
                if (l < 2) {
                    k_gat<0, 1><<<N_NODES / 4, 256, 0, stream>>>(xl, xr, at, bb,
                        ioff, icsr, nullptr, t0b);
                    lin = t0b;
                } else {
                    k_gat<1, 0><<<N_NODES / 4, 256, 0, stream>>>(xl, xr, at, bb,
                        ioff, icsr, brs[mb], nullptr);
                }
            }
        }
        const float* resin = (st == 0) ? xn : img;
        if (st == 2) {
            k_cc<1><<<N_NODES / 128, 256, 0, stream>>>(br0, br1, br2,
                cct + st * 12288, ccb + st * 64, resin, outp, nullptr);
        } else {
            k_cc<0><<<N_NODES / 128, 256, 0, stream>>>(br0, br1, br2,
                cct + st * 12288, ccb + st * 64, resin, img, xb);
            for (int bk = 0; bk < 4; ++bk) {
                int cv = (st * 4 + bk) * 2;
                k_conv<0><<<512, 256, 0, stream>>>(xb, wpkc + (size_t)cv * 36864,
                    rbb + cv * 64, rba + st * 4 + bk, nullptr, cvb);
                k_conv<1><<<512, 256, 0, stream>>>(cvb, wpkc + (size_t)(cv + 1) * 36864,
                    rbb + (cv + 1) * 64, nullptr, img, xb);
            }
        }
    }
}

// Round 3
// 2710.431 us; speedup vs baseline: 2.7115x; 1.0090x over previous
//
#include <hip/hip_runtime.h>
#include <hip/hip_bf16.h>
#include <math.h>

#define N_NODES 65536
#define HW      65536
#define NE      524288
#define NC      (N_NODES * 64)

typedef __bf16 bf16x8 __attribute__((ext_vector_type(8)));
typedef float  f32x4  __attribute__((ext_vector_type(4)));
typedef int    i32x4  __attribute__((ext_vector_type(4)));

static __device__ __forceinline__ f32x4 mfma16(bf16x8 a, bf16x8 b, f32x4 c) {
    return __builtin_amdgcn_mfma_f32_16x16x32_bf16(a, b, c, 0, 0, 0);
}

// ---------------- CSR build ----------------
__global__ void k_hist(const int* __restrict__ dstA, int* __restrict__ cnt) {
    int e = blockIdx.x * 256 + threadIdx.x;
    if (e < NE) atomicAdd(&cnt[dstA[e]], 1);
}

__global__ void k_scan(const int* __restrict__ cnt, int* __restrict__ off) {
    __shared__ int sums[1024];
    int t = threadIdx.x;
    int base = t * 64;
    int s = 0;
    for (int i = 0; i < 64; ++i) s += cnt[base + i];
    sums[t] = s;
    __syncthreads();
    for (int d = 1; d < 1024; d <<= 1) {
        int v = (t >= d) ? sums[t - d] : 0;
        __syncthreads();
        sums[t] += v;
        __syncthreads();
    }
    int run = sums[t] - s;  // exclusive prefix
    for (int i = 0; i < 64; ++i) { off[base + i] = run; run += cnt[base + i]; }
    if (t == 1023) off[N_NODES] = run;
}

__global__ void k_fill(const int* __restrict__ srcA, const int* __restrict__ dstA,
                       int* __restrict__ cur, int* __restrict__ csr) {
    int e = blockIdx.x * 256 + threadIdx.x;
    if (e < NE) {
        int p = atomicAdd(&cur[dstA[e]], 1);
        csr[p] = srcA[e];
    }
}

// ---------------- weight packing (MFMA fragment order) ----------------
// conv: rb_w [16][co][ci][3][3] -> [cv][tap][nt][kk][lane][8] bf16
__global__ void k_cvpack(const float* __restrict__ w, __hip_bfloat16* __restrict__ d) {
    int idx = blockIdx.x * 256 + threadIdx.x;
    if (idx >= 589824) return;
    int j = idx & 7, lane = (idx >> 3) & 63, r = idx >> 9;
    int kk = r & 1; r >>= 1;
    int nt = r & 3; r >>= 2;
    int tap = r % 9, cv = r / 9;
    int co = nt * 16 + (lane & 15);
    int ci = kk * 32 + (lane >> 4) * 8 + j;
    d[idx] = __float2bfloat16(w[((cv * 64 + co) * 64 + ci) * 9 + tap]);
}

// gat mm: gWl/gWr [27][ci][co] -> [lay][side][nt][kk][lane][8] bf16
__global__ void k_mmpack(const float* __restrict__ Wl, const float* __restrict__ Wr,
                         __hip_bfloat16* __restrict__ d) {
    int idx = blockIdx.x * 256 + threadIdx.x;
    if (idx >= 221184) return;
    int j = idx & 7, lane = (idx >> 3) & 63, r = idx >> 9;
    int kk = r & 1; r >>= 1;
    int nt = r & 3; r >>= 2;
    int side = r & 1, lay = r >> 1;
    int co = nt * 16 + (lane & 15);
    int ci = kk * 32 + (lane >> 4) * 8 + j;
    const float* W = side ? Wr : Wl;
    d[idx] = __float2bfloat16(W[lay * 4096 + ci * 64 + co]);
}

// cc_w [3][o=64][k=192] -> cct [3][k=192][o=64]  (fp32)
__global__ void k_cctrans(const float* __restrict__ w, float* __restrict__ wt) {
    int idx = blockIdx.x * 256 + threadIdx.x;
    if (idx >= 3 * 192 * 64) return;
    int o  = idx & 63;
    int k  = (idx >> 6) % 192;
    int ci = idx / (192 * 64);
    wt[idx] = w[ci * 64 * 192 + o * 192 + k];
}

// ---------------- initial NCHW -> [N,64] fp32 + bf16 ----------------
__global__ void k_init(const float* __restrict__ img, float* __restrict__ xn,
                       __hip_bfloat16* __restrict__ xb) {
    __shared__ float tile[64][65];
    int nb = blockIdx.x * 64;
    for (int idx = threadIdx.x; idx < 4096; idx += 256) {
        int c = idx >> 6, n = idx & 63;
        tile[c][n] = img[c * HW + nb + n];
    }
    __syncthreads();
    for (int idx = threadIdx.x; idx < 4096; idx += 256) {
        int n = idx >> 6, c = idx & 63;
        float v = tile[c][n];
        xn[(nb + n) * 64 + c] = v;
        xb[(nb + n) * 64 + c] = __float2bfloat16(v);
    }
}

// ---------------- MFMA dual matmul: XLb = bf16(X@Wl), XR = X@Wr ----------------
__global__ __launch_bounds__(256) void k_mm(const __hip_bfloat16* __restrict__ Xb,
        const __hip_bfloat16* __restrict__ pw, __hip_bfloat16* __restrict__ XLb,
        float* __restrict__ XR) {
    __shared__ i32x4 la[128 * 8];
    int t = threadIdx.x, lane = t & 63, wid = t >> 6;
    int n0 = blockIdx.x * 128;
    const i32x4* Xg = (const i32x4*)Xb + n0 * 8;
    for (int idx = t; idx < 1024; idx += 256) {
        int r = idx >> 3, c = idx & 7;
        la[r * 8 + (c ^ (r & 7))] = Xg[idx];
    }
    int side = wid & 1, rh = wid >> 1;
    const i32x4* wpt = (const i32x4*)pw + side * 512 + lane;
    f32x4 acc[4][4];
#pragma unroll
    for (int mi = 0; mi < 4; ++mi)
#pragma unroll
        for (int nt = 0; nt < 4; ++nt) acc[mi][nt] = (f32x4)0.0f;
    bf16x8 b[4][2];
#pragma unroll
    for (int nt = 0; nt < 4; ++nt)
#pragma unroll
        for (int kk = 0; kk < 2; ++kk)
            b[nt][kk] = __builtin_bit_cast(bf16x8, wpt[(nt * 2 + kk) * 64]);
    __syncthreads();
#pragma unroll
    for (int mi = 0; mi < 4; ++mi) {
        int row = rh * 64 + mi * 16 + (lane & 15);
#pragma unroll
        for (int kk = 0; kk < 2; ++kk) {
            bf16x8 a = __builtin_bit_cast(bf16x8,
                la[row * 8 + (((kk << 2) | (lane >> 4)) ^ (row & 7))]);
#pragma unroll
            for (int nt = 0; nt < 4; ++nt)
                acc[mi][nt] = mfma16(a, b[nt][kk], acc[mi][nt]);
        }
    }
#pragma unroll
    for (int mi = 0; mi < 4; ++mi)
#pragma unroll
        for (int nt = 0; nt < 4; ++nt) {
            int co = nt * 16 + (lane & 15);
#pragma unroll
            for (int r = 0; r < 4; ++r) {
                int node = n0 + rh * 64 + mi * 16 + (lane >> 4) * 4 + r;
                if (side == 0)
                    XLb[node * 64 + co] = __float2bfloat16(acc[mi][nt][r]);
                else
                    XR[node * 64 + co] = acc[mi][nt][r];
            }
        }
}

// ---------------- GAT edge phase: 4 nodes/wave, no-max softmax ----------------
template <int WF32, int WB16>
__global__ __launch_bounds__(256) void k_gat(const __hip_bfloat16* __restrict__ XLb,
        const float* __restrict__ XR, const float* __restrict__ att64,
        const float* __restrict__ bias, const int* __restrict__ off,
        const int* __restrict__ csr, float* __restrict__ outf,
        __hip_bfloat16* __restrict__ outb) {
    int lane = threadIdx.x & 63;
    int nb = (blockIdx.x * 4 + (threadIdx.x >> 6)) * 4;
    float a = att64[lane] * 1.44269504089f;   // fold log2(e): use native exp2
    float b = bias[lane];
    int eo[5];
#pragma unroll
    for (int k = 0; k < 5; ++k) eo[k] = off[nb + k];
    float xi[4], s[4], acc[4];
#pragma unroll
    for (int k = 0; k < 4; ++k) {
        xi[k] = XR[(nb + k) * 64 + lane];
        s[k] = 0.f;
        acc[k] = 0.f;
    }
    int maxd = 0;
#pragma unroll
    for (int k = 0; k < 4; ++k) maxd = max(maxd, eo[k + 1] - eo[k]);
    for (int i = 0; i < maxd; ++i) {
#pragma unroll
        for (int k = 0; k < 4; ++k) {
            int e = eo[k] + i;
            if (e < eo[k + 1]) {              // wave-uniform -> scalar branch
                int src = csr[e];
                float xj = __bfloat162float(XLb[src * 64 + lane]);
                float v = xi[k] + xj;
                v = fmaxf(v, 0.2f * v);       // leaky_relu(0.2)
                float p = v * a;
                p += __shfl_xor(p, 1);
                p += __shfl_xor(p, 2);
                p += __shfl_xor(p, 4);
                p += __shfl_xor(p, 8);
                p = fminf(fmaxf(p, -60.f), 60.f);
                float ex = exp2f(p);          // softmax shift-invariant: no max-sub
                s[k] += ex;
                acc[k] = fmaf(ex, xj, acc[k]);
            }
        }
    }
#pragma unroll
    for (int k = 0; k < 4; ++k) {
        float val = acc[k] / (s[k] + 1e-16f) + b;
        val = val > 0.f ? val : __expf(val) - 1.f;  // ELU
        if constexpr (WF32) outf[(nb + k) * 64 + lane] = val;
        if constexpr (WB16) outb[(nb + k) * 64 + lane] = __float2bfloat16(val);
    }
}

// ---------------- 1x1 conv over 3 branches + bias + residual ----------------
template <int FINAL>
__global__ __launch_bounds__(256) void k_cc(const float* __restrict__ b0,
        const float* __restrict__ b1, const float* __restrict__ b2,
        const float* __restrict__ Wt /*[192][64]*/, const float* __restrict__ bias,
        const float* __restrict__ resin /*[N,64]*/, float* __restrict__ outf,
        __hip_bfloat16* __restrict__ outb) {
    __shared__ float xs[128][65];
    int t = threadIdx.x;
    int n0 = blockIdx.x * 128;
    int wave = t >> 6, lane = t & 63;
    int half = wave >> 1;
    int row  = ((wave & 1) << 6) + lane;
    int hs = __builtin_amdgcn_readfirstlane(half) * 32;
    float acc[32];
#pragma unroll
    for (int j = 0; j < 32; ++j) acc[j] = 0.f;
    const float* brs[3] = {b0, b1, b2};
#pragma unroll
    for (int br = 0; br < 3; ++br) {
        __syncthreads();
        const float* B = brs[br];
        for (int idx = t; idx < 8192; idx += 256) {
            int r = idx >> 6, k = idx & 63;
            xs[r][k] = B[(n0 + r) * 64 + k];
        }
        __syncthreads();
        const float* w = Wt + (br * 64) * 64 + hs;
        for (int k = 0; k < 64; ++k) {
            float xv = xs[row][k];
#pragma unroll
            for (int j = 0; j < 32; ++j) acc[j] += xv * w[k * 64 + j];
        }
    }
    int node = n0 + row;
#pragma unroll
    for (int j = 0; j < 32; ++j) {
        int o = hs + j;
        float v = acc[j] + bias[o] + resin[node * 64 + o];
        if (FINAL) {
            outf[o * HW + node] = v;   // NCHW final output
        } else {
            outf[node * 64 + o] = v;
            outb[node * 64 + o] = __float2bfloat16(v);
        }
    }
}

// ---------------- 3x3 conv 64->64, channels-last, MFMA ----------------
// MODE 0: outb = bf16(prelu(conv+b));  MODE 1: img += conv+b (fp32), outb = bf16(img)
template <int MODE>
__global__ __launch_bounds__(256) void k_conv(const __hip_bfloat16* __restrict__ inb,
        const __hip_bfloat16* __restrict__ wp, const float* __restrict__ bias,
        const float* __restrict__ pa, float* __restrict__ img,
        __hip_bfloat16* __restrict__ outb) {
    __shared__ i32x4 la[130 * 8];
    int t = threadIdx.x, lane = t & 63, wid = t >> 6;
    int y = blockIdx.x >> 1, x0 = (blockIdx.x & 1) << 7;
    f32x4 acc[2][4];
#pragma unroll
    for (int mi = 0; mi < 2; ++mi)
#pragma unroll
        for (int nt = 0; nt < 4; ++nt) acc[mi][nt] = (f32x4)0.0f;
    const i32x4* ing = (const i32x4*)inb;
#pragma unroll
    for (int dy = 0; dy < 3; ++dy) {
        int sy = y + dy - 1;
        bool rowok = (sy >= 0) && (sy < 256);
        __syncthreads();
        for (int idx = t; idx < 1040; idx += 256) {
            int r = idx >> 3, c = idx & 7;
            int sx = x0 - 1 + r;
            i32x4 v = (i32x4)0;
            if (rowok && sx >= 0 && sx < 256) v = ing[(sy * 256 + sx) * 8 + c];
            la[r * 8 + (c ^ (r & 7))] = v;
        }
        __syncthreads();
#pragma unroll
        for (int dx = 0; dx < 3; ++dx) {
            const i32x4* wpt = (const i32x4*)wp + (dy * 3 + dx) * 512 + lane;
            bf16x8 b[4][2];
#pragma unroll
            for (int nt = 0; nt < 4; ++nt)
#pragma unroll
                for (int kk = 0; kk < 2; ++kk)
                    b[nt][kk] = __builtin_bit_cast(bf16x8, wpt[(nt * 2 + kk) * 64]);
#pragma unroll
            for (int mi = 0; mi < 2; ++mi) {
                int row = dx + wid * 32 + mi * 16 + (lane & 15);
#pragma unroll
                for (int kk = 0; kk < 2; ++kk) {
                    bf16x8 a = __builtin_bit_cast(bf16x8,
                        la[row * 8 + (((kk << 2) | (lane >> 4)) ^ (row & 7))]);
#pragma unroll
                    for (int nt = 0; nt < 4; ++nt)
                        acc[mi][nt] = mfma16(a, b[nt][kk], acc[mi][nt]);
                }
            }
        }
    }
    int pbase = y * 256 + x0 + wid * 32 + (lane >> 4) * 4;
    float aprelu = (MODE == 0) ? pa[0] : 0.f;
#pragma unroll
    for (int mi = 0; mi < 2; ++mi)
#pragma unroll
        for (int nt = 0; nt < 4; ++nt) {
            int co = nt * 16 + (lane & 15);
            float bv = bias[co];
#pragma unroll
            for (int r = 0; r < 4; ++r) {
                int pix = pbase + mi * 16 + r;
                float v = acc[mi][nt][r] + bv;
                if (MODE == 0) {
                    v = v >= 0.f ? v : aprelu * v;
                    outb[pix * 64 + co] = __float2bfloat16(v);
                } else {
                    v += img[pix * 64 + co];
                    img[pix * 64 + co] = v;
                    outb[pix * 64 + co] = __float2bfloat16(v);
                }
            }
        }
}

// ---------------- host ----------------
extern "C" void kernel_launch(void* const* d_in, const int* in_sizes, int n_in,
                              void* d_out, int out_size, void* d_ws, size_t ws_size,
                              hipStream_t stream) {
    const float* x    = (const float*)d_in[0];
    const int*   ei   = (const int*)d_in[1];
    const float* gWl  = (const float*)d_in[2];   // [27][64][64]
    const float* gWr  = (const float*)d_in[3];
    const float* gatt = (const float*)d_in[4];   // [27][64]
    const float* gb   = (const float*)d_in[5];   // [27][64]
    const float* ccw  = (const float*)d_in[6];   // [3][64][192]
    const float* ccb  = (const float*)d_in[7];   // [3][64]
    const float* rbw  = (const float*)d_in[8];   // [16][64][64][3][3]
    const float* rbb  = (const float*)d_in[9];   // [16][64]
    const float* rba  = (const float*)d_in[10];  // [8]
    float* outp = (float*)d_out;

    float* wsf = (float*)d_ws;
    float* xn  = wsf;            // [N,64] fp32 stage-0 residual
    float* br0 = xn  + NC;
    float* br1 = br0 + NC;
    float* br2 = br1 + NC;
    float* xl  = br2 + NC;       // used as bf16 XLb
    float* xr  = xl  + NC;
    float* img = xr  + NC;       // [N,64] fp32 running image
    float* cct = img + NC;       // 36864
    __hip_bfloat16* xlb  = (__hip_bfloat16*)xl;
    __hip_bfloat16* xb   = (__hip_bfloat16*)(cct + 36864);  // NC bf16
    __hip_bfloat16* t0b  = xb  + NC;
    __hip_bfloat16* cvb  = t0b + NC;
    __hip_bfloat16* wpkc = cvb + NC;        // 589824
    __hip_bfloat16* wpkm = wpkc + 589824;   // 221184
    int* ioff = (int*)(wpkm + 221184);
    int* icnt = ioff + (N_NODES + 1);
    int* icur = icnt + N_NODES;
    int* icsr = icur + N_NODES;             // NE

    const int* srcA = ei;
    const int* dstA = ei + NE;

    hipMemsetAsync(icnt, 0, N_NODES * sizeof(int), stream);
    k_hist<<<NE / 256, 256, 0, stream>>>(dstA, icnt);
    k_scan<<<1, 1024, 0, stream>>>(icnt, ioff);
    hipMemcpyAsync(icur, ioff, N_NODES * sizeof(int), hipMemcpyDeviceToDevice, stream);
    k_fill<<<NE / 256, 256, 0, stream>>>(srcA, dstA, icur, icsr);
    k_cvpack<<<2304, 256, 0, stream>>>(rbw, wpkc);
    k_mmpack<<<864, 256, 0, stream>>>(gWl, gWr, wpkm);
    k_cctrans<<<144, 256, 0, stream>>>(ccw, cct);
    k_init<<<1024, 256, 0, stream>>>(x, xn, xb);

    float* brs[3] = {br0, br1, br2};
    for (int st = 0; st < 3; ++st) {
        for (int mb = 0; mb < 3; ++mb) {
            const __hip_bfloat16* lin = xb;
            for (int l = 0; l < 3; ++l) {
                int lay = (st * 3 + mb) * 3 + l;
                k_mm<<<N_NODES / 128, 256, 0, stream>>>(lin, wpkm + lay * 8192, xlb, xr);
                const float* at = gatt + lay * 64;
                const float* bb = gb + lay * 64;
                if (l < 2) {
                    k_gat<0, 1><<<N_NODES / 16, 256, 0, stream>>>(xlb, xr, at, bb,
                        ioff, icsr, nullptr, t0b);
                    lin = t0b;
                } else {
                    k_gat<1, 0><<<N_NODES / 16, 256, 0, stream>>>(xlb, xr, at, bb,
                        ioff, icsr, brs[mb], nullptr);
                }
            }
        }
        const float* resin = (st == 0) ? xn : img;
        if (st == 2) {
            k_cc<1><<<N_NODES / 128, 256, 0, stream>>>(br0, br1, br2,
                cct + st * 12288, ccb + st * 64, resin, outp, nullptr);
        } else {
            k_cc<0><<<N_NODES / 128, 256, 0, stream>>>(br0, br1, br2,
                cct + st * 12288, ccb + st * 64, resin, img, xb);
            for (int bk = 0; bk < 4; ++bk) {
                int cv = (st * 4 + bk) * 2;
                k_conv<0><<<512, 256, 0, stream>>>(xb, wpkc + (size_t)cv * 36864,
                    rbb + cv * 64, rba + st * 4 + bk, nullptr, cvb);
                k_conv<1><<<512, 256, 0, stream>>>(cvb, wpkc + (size_t)(cv + 1) * 36864,
                    rbb + (cv + 1) * 64, nullptr, img, xb);
            }
        }
    }
}

// Round 4
// 1663.299 us; speedup vs baseline: 4.4185x; 1.6296x over previous
//
#include <hip/hip_runtime.h>
#include <hip/hip_bf16.h>
#include <math.h>

#define N_NODES 65536
#define HW      65536
#define NE      524288
#define NC      (N_NODES * 64)

typedef __bf16 bf16x8 __attribute__((ext_vector_type(8)));
typedef float  f32x4  __attribute__((ext_vector_type(4)));
typedef int    i32x4  __attribute__((ext_vector_type(4)));
typedef unsigned int uint2v __attribute__((ext_vector_type(2)));

static __device__ __forceinline__ f32x4 mfma16(bf16x8 a, bf16x8 b, f32x4 c) {
    return __builtin_amdgcn_mfma_f32_16x16x32_bf16(a, b, c, 0, 0, 0);
}

static __device__ __forceinline__ unsigned short f2bs(float f) {
    return __builtin_bit_cast(unsigned short, __float2bfloat16(f));
}

// ---------------- CSR build ----------------
__global__ void k_hist(const int* __restrict__ dstA, int* __restrict__ cnt) {
    int e = blockIdx.x * 256 + threadIdx.x;
    if (e < NE) atomicAdd(&cnt[dstA[e]], 1);
}

__global__ void k_scan(const int* __restrict__ cnt, int* __restrict__ off) {
    __shared__ int sums[1024];
    int t = threadIdx.x;
    int base = t * 64;
    int s = 0;
    for (int i = 0; i < 64; ++i) s += cnt[base + i];
    sums[t] = s;
    __syncthreads();
    for (int d = 1; d < 1024; d <<= 1) {
        int v = (t >= d) ? sums[t - d] : 0;
        __syncthreads();
        sums[t] += v;
        __syncthreads();
    }
    int run = sums[t] - s;  // exclusive prefix
    for (int i = 0; i < 64; ++i) { off[base + i] = run; run += cnt[base + i]; }
    if (t == 1023) off[N_NODES] = run;
}

__global__ void k_fill(const int* __restrict__ srcA, const int* __restrict__ dstA,
                       int* __restrict__ cur, int* __restrict__ csr) {
    int e = blockIdx.x * 256 + threadIdx.x;
    if (e < NE) {
        int p = atomicAdd(&cur[dstA[e]], 1);
        csr[p] = srcA[e];
    }
}

// ---------------- weight packing (MFMA fragment order) ----------------
// conv: rb_w [16][co][ci][3][3] -> [cv][tap][nt][kk][lane][8] bf16
__global__ void k_cvpack(const float* __restrict__ w, __hip_bfloat16* __restrict__ d) {
    int idx = blockIdx.x * 256 + threadIdx.x;
    if (idx >= 589824) return;
    int j = idx & 7, lane = (idx >> 3) & 63, r = idx >> 9;
    int kk = r & 1; r >>= 1;
    int nt = r & 3; r >>= 2;
    int tap = r % 9, cv = r / 9;
    int co = nt * 16 + (lane & 15);
    int ci = kk * 32 + (lane >> 4) * 8 + j;
    d[idx] = __float2bfloat16(w[((cv * 64 + co) * 64 + ci) * 9 + tap]);
}

// gat mm: gWl/gWr [27][ci][co] -> [lay][side][nt][kk][lane][8] bf16
__global__ void k_mmpack(const float* __restrict__ Wl, const float* __restrict__ Wr,
                         __hip_bfloat16* __restrict__ d) {
    int idx = blockIdx.x * 256 + threadIdx.x;
    if (idx >= 221184) return;
    int j = idx & 7, lane = (idx >> 3) & 63, r = idx >> 9;
    int kk = r & 1; r >>= 1;
    int nt = r & 3; r >>= 2;
    int side = r & 1, lay = r >> 1;
    int co = nt * 16 + (lane & 15);
    int ci = kk * 32 + (lane >> 4) * 8 + j;
    const float* W = side ? Wr : Wl;
    d[idx] = __float2bfloat16(W[lay * 4096 + ci * 64 + co]);
}

// cc_w [3][o=64][k=192] -> cct [3][k=192][o=64]  (fp32)
__global__ void k_cctrans(const float* __restrict__ w, float* __restrict__ wt) {
    int idx = blockIdx.x * 256 + threadIdx.x;
    if (idx >= 3 * 192 * 64) return;
    int o  = idx & 63;
    int k  = (idx >> 6) % 192;
    int ci = idx / (192 * 64);
    wt[idx] = w[ci * 64 * 192 + o * 192 + k];
}

// ---------------- initial NCHW -> [N,64] fp32 + bf16 ----------------
__global__ void k_init(const float* __restrict__ img, float* __restrict__ xn,
                       __hip_bfloat16* __restrict__ xb) {
    __shared__ float tile[64][65];
    int nb = blockIdx.x * 64;
    for (int idx = threadIdx.x; idx < 4096; idx += 256) {
        int c = idx >> 6, n = idx & 63;
        tile[c][n] = img[c * HW + nb + n];
    }
    __syncthreads();
    for (int idx = threadIdx.x; idx < 4096; idx += 256) {
        int n = idx >> 6, c = idx & 63;
        float v = tile[c][n];
        xn[(nb + n) * 64 + c] = v;
        xb[(nb + n) * 64 + c] = __float2bfloat16(v);
    }
}

// ---------------- MFMA dual matmul: XLb = bf16(X@Wl), XR = X@Wr ----------------
__global__ __launch_bounds__(256) void k_mm(const __hip_bfloat16* __restrict__ Xb,
        const __hip_bfloat16* __restrict__ pw, __hip_bfloat16* __restrict__ XLb,
        float* __restrict__ XR) {
    __shared__ i32x4 la[128 * 8];
    int t = threadIdx.x, lane = t & 63, wid = t >> 6;
    int n0 = blockIdx.x * 128;
    const i32x4* Xg = (const i32x4*)Xb + n0 * 8;
    for (int idx = t; idx < 1024; idx += 256) {
        int r = idx >> 3, c = idx & 7;
        la[r * 8 + (c ^ (r & 7))] = Xg[idx];
    }
    int side = wid & 1, rh = wid >> 1;
    const i32x4* wpt = (const i32x4*)pw + side * 512 + lane;
    f32x4 acc[4][4];
#pragma unroll
    for (int mi = 0; mi < 4; ++mi)
#pragma unroll
        for (int nt = 0; nt < 4; ++nt) acc[mi][nt] = (f32x4)0.0f;
    bf16x8 b[4][2];
#pragma unroll
    for (int nt = 0; nt < 4; ++nt)
#pragma unroll
        for (int kk = 0; kk < 2; ++kk)
            b[nt][kk] = __builtin_bit_cast(bf16x8, wpt[(nt * 2 + kk) * 64]);
    __syncthreads();
#pragma unroll
    for (int mi = 0; mi < 4; ++mi) {
        int row = rh * 64 + mi * 16 + (lane & 15);
#pragma unroll
        for (int kk = 0; kk < 2; ++kk) {
            bf16x8 a = __builtin_bit_cast(bf16x8,
                la[row * 8 + (((kk << 2) | (lane >> 4)) ^ (row & 7))]);
#pragma unroll
            for (int nt = 0; nt < 4; ++nt)
                acc[mi][nt] = mfma16(a, b[nt][kk], acc[mi][nt]);
        }
    }
#pragma unroll
    for (int mi = 0; mi < 4; ++mi)
#pragma unroll
        for (int nt = 0; nt < 4; ++nt) {
            int co = nt * 16 + (lane & 15);
#pragma unroll
            for (int r = 0; r < 4; ++r) {
                int node = n0 + rh * 64 + mi * 16 + (lane >> 4) * 4 + r;
                if (side == 0)
                    XLb[node * 64 + co] = __float2bfloat16(acc[mi][nt][r]);
                else
                    XR[node * 64 + co] = acc[mi][nt][r];
            }
        }
}

// ---------------- GAT edge phase: 4 edges x 16 lanes, 4 channels/lane ----------------
// lane = 16*g + q, g = edge-group (0..3), channels (lane&15)*4 .. +3
template <int WF32, int WB16>
__global__ __launch_bounds__(256) void k_gat(const __hip_bfloat16* __restrict__ XLb,
        const float* __restrict__ XR, const float* __restrict__ att64,
        const float* __restrict__ bias, const int* __restrict__ off,
        const int* __restrict__ csr, float* __restrict__ outf,
        __hip_bfloat16* __restrict__ outb) {
    int lane = threadIdx.x & 63;
    int g  = lane >> 4;
    int c4 = (lane & 15) << 2;
    f32x4 a4 = *(const f32x4*)(att64 + c4);
    const float LOG2E = 1.44269504089f;
    a4[0] *= LOG2E; a4[1] *= LOG2E; a4[2] *= LOG2E; a4[3] *= LOG2E;
    f32x4 b4 = *(const f32x4*)(bias + c4);
    int wave = blockIdx.x * 4 + ((threadIdx.x >> 6) & 3);
    int n0 = wave * 8;
    for (int n = n0; n < n0 + 8; ++n) {
        int e0 = off[n], e1 = off[n + 1];
        f32x4 xi = *(const f32x4*)(XR + n * 64 + c4);
        float s = 0.f;
        f32x4 acc = (f32x4)0.0f;
        int iters = (e1 - e0 + 3) >> 2;
        int e1m1 = e1 - 1;
        int e = e0 + g;
        for (int i = 0; i < iters; ++i, e += 4) {
            bool act = e < e1;
            int ec = act ? e : e1m1;
            int src = csr[ec];
            uint2v xw = *(const uint2v*)(XLb + src * 64 + c4);
            f32x4 xj;
            xj[0] = __builtin_bit_cast(float, xw[0] << 16);
            xj[1] = __builtin_bit_cast(float, xw[0] & 0xffff0000u);
            xj[2] = __builtin_bit_cast(float, xw[1] << 16);
            xj[3] = __builtin_bit_cast(float, xw[1] & 0xffff0000u);
            float pp = 0.f;
#pragma unroll
            for (int j = 0; j < 4; ++j) {
                float v = xi[j] + xj[j];
                v = fmaxf(v, 0.2f * v);          // leaky_relu(0.2)
                pp = fmaf(v, a4[j], pp);
            }
            pp += __shfl_xor(pp, 1);
            pp += __shfl_xor(pp, 2);             // head logit (quad reduce)
            pp = fminf(fmaxf(pp, -60.f), 60.f);
            float ex = exp2f(pp);                // shift-invariant softmax, no max-sub
            ex = act ? ex : 0.f;
            s += ex;
#pragma unroll
            for (int j = 0; j < 4; ++j) acc[j] = fmaf(ex, xj[j], acc[j]);
        }
        // cross-group reduce: lanes ^16, ^32
        s += __shfl_xor(s, 16);
        s += __shfl_xor(s, 32);
#pragma unroll
        for (int j = 0; j < 4; ++j) {
            acc[j] += __shfl_xor(acc[j], 16);
            acc[j] += __shfl_xor(acc[j], 32);
        }
        float inv = 1.f / (s + 1e-16f);
        f32x4 val;
#pragma unroll
        for (int j = 0; j < 4; ++j) {
            float v = acc[j] * inv + b4[j];
            val[j] = v > 0.f ? v : __expf(v) - 1.f;  // ELU
        }
        if constexpr (WF32) {
            *(f32x4*)(outf + n * 64 + c4) = val;
        }
        if constexpr (WB16) {
            uint2v o;
            o[0] = (unsigned)f2bs(val[0]) | ((unsigned)f2bs(val[1]) << 16);
            o[1] = (unsigned)f2bs(val[2]) | ((unsigned)f2bs(val[3]) << 16);
            *(uint2v*)(outb + n * 64 + c4) = o;
        }
    }
}

// ---------------- 1x1 conv over 3 branches + bias + residual ----------------
template <int FINAL>
__global__ __launch_bounds__(256) void k_cc(const float* __restrict__ b0,
        const float* __restrict__ b1, const float* __restrict__ b2,
        const float* __restrict__ Wt /*[192][64]*/, const float* __restrict__ bias,
        const float* __restrict__ resin /*[N,64]*/, float* __restrict__ outf,
        __hip_bfloat16* __restrict__ outb) {
    __shared__ float xs[128][65];
    int t = threadIdx.x;
    int n0 = blockIdx.x * 128;
    int wave = t >> 6, lane = t & 63;
    int half = wave >> 1;
    int row  = ((wave & 1) << 6) + lane;
    int hs = __builtin_amdgcn_readfirstlane(half) * 32;
    float acc[32];
#pragma unroll
    for (int j = 0; j < 32; ++j) acc[j] = 0.f;
    const float* brs[3] = {b0, b1, b2};
#pragma unroll
    for (int br = 0; br < 3; ++br) {
        __syncthreads();
        const float* B = brs[br];
        for (int idx = t; idx < 8192; idx += 256) {
            int r = idx >> 6, k = idx & 63;
            xs[r][k] = B[(n0 + r) * 64 + k];
        }
        __syncthreads();
        const float* w = Wt + (br * 64) * 64 + hs;
        for (int k = 0; k < 64; ++k) {
            float xv = xs[row][k];
#pragma unroll
            for (int j = 0; j < 32; ++j) acc[j] += xv * w[k * 64 + j];
        }
    }
    int node = n0 + row;
#pragma unroll
    for (int j = 0; j < 32; ++j) {
        int o = hs + j;
        float v = acc[j] + bias[o] + resin[node * 64 + o];
        if (FINAL) {
            outf[o * HW + node] = v;   // NCHW final output
        } else {
            outf[node * 64 + o] = v;
            outb[node * 64 + o] = __float2bfloat16(v);
        }
    }
}

// ---------------- 3x3 conv 64->64, channels-last, MFMA ----------------
// MODE 0: outb = bf16(prelu(conv+b));  MODE 1: img += conv+b (fp32), outb = bf16(img)
template <int MODE>
__global__ __launch_bounds__(256) void k_conv(const __hip_bfloat16* __restrict__ inb,
        const __hip_bfloat16* __restrict__ wp, const float* __restrict__ bias,
        const float* __restrict__ pa, float* __restrict__ img,
        __hip_bfloat16* __restrict__ outb) {
    __shared__ i32x4 la[130 * 8];
    int t = threadIdx.x, lane = t & 63, wid = t >> 6;
    int y = blockIdx.x >> 1, x0 = (blockIdx.x & 1) << 7;
    f32x4 acc[2][4];
#pragma unroll
    for (int mi = 0; mi < 2; ++mi)
#pragma unroll
        for (int nt = 0; nt < 4; ++nt) acc[mi][nt] = (f32x4)0.0f;
    const i32x4* ing = (const i32x4*)inb;
#pragma unroll
    for (int dy = 0; dy < 3; ++dy) {
        int sy = y + dy - 1;
        bool rowok = (sy >= 0) && (sy < 256);
        __syncthreads();
        for (int idx = t; idx < 1040; idx += 256) {
            int r = idx >> 3, c = idx & 7;
            int sx = x0 - 1 + r;
            i32x4 v = (i32x4)0;
            if (rowok && sx >= 0 && sx < 256) v = ing[(sy * 256 + sx) * 8 + c];
            la[r * 8 + (c ^ (r & 7))] = v;
        }
        __syncthreads();
#pragma unroll
        for (int dx = 0; dx < 3; ++dx) {
            const i32x4* wpt = (const i32x4*)wp + (dy * 3 + dx) * 512 + lane;
            bf16x8 b[4][2];
#pragma unroll
            for (int nt = 0; nt < 4; ++nt)
#pragma unroll
                for (int kk = 0; kk < 2; ++kk)
                    b[nt][kk] = __builtin_bit_cast(bf16x8, wpt[(nt * 2 + kk) * 64]);
#pragma unroll
            for (int mi = 0; mi < 2; ++mi) {
                int row = dx + wid * 32 + mi * 16 + (lane & 15);
#pragma unroll
                for (int kk = 0; kk < 2; ++kk) {
                    bf16x8 a = __builtin_bit_cast(bf16x8,
                        la[row * 8 + (((kk << 2) | (lane >> 4)) ^ (row & 7))]);
#pragma unroll
                    for (int nt = 0; nt < 4; ++nt)
                        acc[mi][nt] = mfma16(a, b[nt][kk], acc[mi][nt]);
                }
            }
        }
    }
    int pbase = y * 256 + x0 + wid * 32 + (lane >> 4) * 4;
    float aprelu = (MODE == 0) ? pa[0] : 0.f;
#pragma unroll
    for (int mi = 0; mi < 2; ++mi)
#pragma unroll
        for (int nt = 0; nt < 4; ++nt) {
            int co = nt * 16 + (lane & 15);
            float bv = bias[co];
#pragma unroll
            for (int r = 0; r < 4; ++r) {
                int pix = pbase + mi * 16 + r;
                float v = acc[mi][nt][r] + bv;
                if (MODE == 0) {
                    v = v >= 0.f ? v : aprelu * v;
                    outb[pix * 64 + co] = __float2bfloat16(v);
                } else {
                    v += img[pix * 64 + co];
                    img[pix * 64 + co] = v;
                    outb[pix * 64 + co] = __float2bfloat16(v);
                }
            }
        }
}

// ---------------- host ----------------
extern "C" void kernel_launch(void* const* d_in, const int* in_sizes, int n_in,
                              void* d_out, int out_size, void* d_ws, size_t ws_size,
                              hipStream_t stream) {
    const float* x    = (const float*)d_in[0];
    const int*   ei   = (const int*)d_in[1];
    const float* gWl  = (const float*)d_in[2];   // [27][64][64]
    const float* gWr  = (const float*)d_in[3];
    const float* gatt = (const float*)d_in[4];   // [27][64]
    const float* gb   = (const float*)d_in[5];   // [27][64]
    const float* ccw  = (const float*)d_in[6];   // [3][64][192]
    const float* ccb  = (const float*)d_in[7];   // [3][64]
    const float* rbw  = (const float*)d_in[8];   // [16][64][64][3][3]
    const float* rbb  = (const float*)d_in[9];   // [16][64]
    const float* rba  = (const float*)d_in[10];  // [8]
    float* outp = (float*)d_out;

    float* wsf = (float*)d_ws;
    float* xn  = wsf;            // [N,64] fp32 stage-0 residual
    float* br0 = xn  + NC;
    float* br1 = br0 + NC;
    float* br2 = br1 + NC;
    float* xl  = br2 + NC;       // used as bf16 XLb
    float* xr  = xl  + NC;
    float* img = xr  + NC;       // [N,64] fp32 running image
    float* cct = img + NC;       // 36864
    __hip_bfloat16* xlb  = (__hip_bfloat16*)xl;
    __hip_bfloat16* xb   = (__hip_bfloat16*)(cct + 36864);  // NC bf16
    __hip_bfloat16* t0b  = xb  + NC;
    __hip_bfloat16* cvb  = t0b + NC;
    __hip_bfloat16* wpkc = cvb + NC;        // 589824
    __hip_bfloat16* wpkm = wpkc + 589824;   // 221184
    int* ioff = (int*)(wpkm + 221184);
    int* icnt = ioff + (N_NODES + 1);
    int* icur = icnt + N_NODES;
    int* icsr = icur + N_NODES;             // NE

    const int* srcA = ei;
    const int* dstA = ei + NE;

    hipMemsetAsync(icnt, 0, N_NODES * sizeof(int), stream);
    k_hist<<<NE / 256, 256, 0, stream>>>(dstA, icnt);
    k_scan<<<1, 1024, 0, stream>>>(icnt, ioff);
    hipMemcpyAsync(icur, ioff, N_NODES * sizeof(int), hipMemcpyDeviceToDevice, stream);
    k_fill<<<NE / 256, 256, 0, stream>>>(srcA, dstA, icur, icsr);
    k_cvpack<<<2304, 256, 0, stream>>>(rbw, wpkc);
    k_mmpack<<<864, 256, 0, stream>>>(gWl, gWr, wpkm);
    k_cctrans<<<144, 256, 0, stream>>>(ccw, cct);
    k_init<<<1024, 256, 0, stream>>>(x, xn, xb);

    float* brs[3] = {br0, br1, br2};
    for (int st = 0; st < 3; ++st) {
        for (int mb = 0; mb < 3; ++mb) {
            const __hip_bfloat16* lin = xb;
            for (int l = 0; l < 3; ++l) {
                int lay = (st * 3 + mb) * 3 + l;
                k_mm<<<N_NODES / 128, 256, 0, stream>>>(lin, wpkm + lay * 8192, xlb, xr);
                const float* at = gatt + lay * 64;
                const float* bb = gb + lay * 64;
                if (l < 2) {
                    k_gat<0, 1><<<2048, 256, 0, stream>>>(xlb, xr, at, bb,
                        ioff, icsr, nullptr, t0b);
                    lin = t0b;
                } else {
                    k_gat<1, 0><<<2048, 256, 0, stream>>>(xlb, xr, at, bb,
                        ioff, icsr, brs[mb], nullptr);
                }
            }
        }
        const float* resin = (st == 0) ? xn : img;
        if (st == 2) {
            k_cc<1><<<N_NODES / 128, 256, 0, stream>>>(br0, br1, br2,
                cct + st * 12288, ccb + st * 64, resin, outp, nullptr);
        } else {
            k_cc<0><<<N_NODES / 128, 256, 0, stream>>>(br0, br1, br2,
                cct + st * 12288, ccb + st * 64, resin, img, xb);
            for (int bk = 0; bk < 4; ++bk) {
                int cv = (st * 4 + bk) * 2;
                k_conv<0><<<512, 256, 0, stream>>>(xb, wpkc + (size_t)cv * 36864,
                    rbb + cv * 64, rba + st * 4 + bk, nullptr, cvb);
                k_conv<1><<<512, 256, 0, stream>>>(cvb, wpkc + (size_t)(cv + 1) * 36864,
                    rbb + (cv + 1) * 64, nullptr, img, xb);
            }
        }
    }
}

// Round 5
// 1518.713 us; speedup vs baseline: 4.8392x; 1.0952x over previous
//
#include <hip/hip_runtime.h>
#include <hip/hip_bf16.h>
#include <math.h>

#define N_NODES 65536
#define HW      65536
#define NE      524288
#define NC      (N_NODES * 64)

typedef __bf16 bf16x8 __attribute__((ext_vector_type(8)));
typedef float  f32x4  __attribute__((ext_vector_type(4)));
typedef int    i32x4  __attribute__((ext_vector_type(4)));
typedef unsigned int uint2v __attribute__((ext_vector_type(2)));

static __device__ __forceinline__ f32x4 mfma16(bf16x8 a, bf16x8 b, f32x4 c) {
    return __builtin_amdgcn_mfma_f32_16x16x32_bf16(a, b, c, 0, 0, 0);
}

static __device__ __forceinline__ unsigned short f2bs(float f) {
    return __builtin_bit_cast(unsigned short, __float2bfloat16(f));
}

static __device__ __forceinline__ void unpack4(uint2v xw, f32x4& xj) {
    xj[0] = __builtin_bit_cast(float, xw[0] << 16);
    xj[1] = __builtin_bit_cast(float, xw[0] & 0xffff0000u);
    xj[2] = __builtin_bit_cast(float, xw[1] << 16);
    xj[3] = __builtin_bit_cast(float, xw[1] & 0xffff0000u);
}

// ---------------- CSR build ----------------
__global__ void k_hist(const int* __restrict__ dstA, int* __restrict__ cnt) {
    int e = blockIdx.x * 256 + threadIdx.x;
    if (e < NE) atomicAdd(&cnt[dstA[e]], 1);
}

__global__ void k_scan(const int* __restrict__ cnt, int* __restrict__ off) {
    __shared__ int sums[1024];
    int t = threadIdx.x;
    int base = t * 64;
    int s = 0;
    for (int i = 0; i < 64; ++i) s += cnt[base + i];
    sums[t] = s;
    __syncthreads();
    for (int d = 1; d < 1024; d <<= 1) {
        int v = (t >= d) ? sums[t - d] : 0;
        __syncthreads();
        sums[t] += v;
        __syncthreads();
    }
    int run = sums[t] - s;  // exclusive prefix
    for (int i = 0; i < 64; ++i) { off[base + i] = run; run += cnt[base + i]; }
    if (t == 1023) off[N_NODES] = run;
}

__global__ void k_fill(const int* __restrict__ srcA, const int* __restrict__ dstA,
                       int* __restrict__ cur, int* __restrict__ csr) {
    int e = blockIdx.x * 256 + threadIdx.x;
    if (e < NE) {
        int p = atomicAdd(&cur[dstA[e]], 1);
        csr[p] = srcA[e];
    }
}

// ---------------- weight packing (MFMA fragment order) ----------------
// conv: rb_w [16][co][ci][3][3] -> [cv][tap][nt][kk][lane][8] bf16
__global__ void k_cvpack(const float* __restrict__ w, __hip_bfloat16* __restrict__ d) {
    int idx = blockIdx.x * 256 + threadIdx.x;
    if (idx >= 589824) return;
    int j = idx & 7, lane = (idx >> 3) & 63, r = idx >> 9;
    int kk = r & 1; r >>= 1;
    int nt = r & 3; r >>= 2;
    int tap = r % 9, cv = r / 9;
    int co = nt * 16 + (lane & 15);
    int ci = kk * 32 + (lane >> 4) * 8 + j;
    d[idx] = __float2bfloat16(w[((cv * 64 + co) * 64 + ci) * 9 + tap]);
}

// gat mm: gWl/gWr [27][ci][co] -> [lay][side][nt][kk][lane][8] bf16
__global__ void k_mmpack(const float* __restrict__ Wl, const float* __restrict__ Wr,
                         __hip_bfloat16* __restrict__ d) {
    int idx = blockIdx.x * 256 + threadIdx.x;
    if (idx >= 221184) return;
    int j = idx & 7, lane = (idx >> 3) & 63, r = idx >> 9;
    int kk = r & 1; r >>= 1;
    int nt = r & 3; r >>= 2;
    int side = r & 1, lay = r >> 1;
    int co = nt * 16 + (lane & 15);
    int ci = kk * 32 + (lane >> 4) * 8 + j;
    const float* W = side ? Wr : Wl;
    d[idx] = __float2bfloat16(W[lay * 4096 + ci * 64 + co]);
}

// cc_w [3][o=64][k=192] -> [st][br][nt][kk][lane][8] bf16
__global__ void k_ccpack(const float* __restrict__ w, __hip_bfloat16* __restrict__ d) {
    int idx = blockIdx.x * 256 + threadIdx.x;
    if (idx >= 36864) return;
    int j = idx & 7;
    int u = idx >> 3;
    int lane = u & 63;
    int f = (u >> 6) & 7;
    int sb = u >> 9;
    int kk = f & 1, nt = f >> 1;
    int br = sb % 3, st = sb / 3;
    int k = br * 64 + kk * 32 + (lane >> 4) * 8 + j;
    int co = nt * 16 + (lane & 15);
    d[idx] = __float2bfloat16(w[st * 12288 + co * 192 + k]);
}

// ---------------- initial NCHW -> [N,64] fp32 + bf16 ----------------
__global__ void k_init(const float* __restrict__ img, float* __restrict__ xn,
                       __hip_bfloat16* __restrict__ xb) {
    __shared__ float tile[64][65];
    int nb = blockIdx.x * 64;
    for (int idx = threadIdx.x; idx < 4096; idx += 256) {
        int c = idx >> 6, n = idx & 63;
        tile[c][n] = img[c * HW + nb + n];
    }
    __syncthreads();
    for (int idx = threadIdx.x; idx < 4096; idx += 256) {
        int n = idx >> 6, c = idx & 63;
        float v = tile[c][n];
        xn[(nb + n) * 64 + c] = v;
        xb[(nb + n) * 64 + c] = __float2bfloat16(v);
    }
}

// ---------------- MFMA dual matmul: XLb = bf16(X@Wl), XR = X@Wr ----------------
__global__ __launch_bounds__(256) void k_mm(const __hip_bfloat16* __restrict__ Xb,
        const __hip_bfloat16* __restrict__ pw, __hip_bfloat16* __restrict__ XLb,
        float* __restrict__ XR) {
    __shared__ i32x4 la[128 * 8];
    int t = threadIdx.x, lane = t & 63, wid = t >> 6;
    int n0 = blockIdx.x * 128;
    const i32x4* Xg = (const i32x4*)Xb + n0 * 8;
    for (int idx = t; idx < 1024; idx += 256) {
        int r = idx >> 3, c = idx & 7;
        la[r * 8 + (c ^ (r & 7))] = Xg[idx];
    }
    int side = wid & 1, rh = wid >> 1;
    const i32x4* wpt = (const i32x4*)pw + side * 512 + lane;
    f32x4 acc[4][4];
#pragma unroll
    for (int mi = 0; mi < 4; ++mi)
#pragma unroll
        for (int nt = 0; nt < 4; ++nt) acc[mi][nt] = (f32x4)0.0f;
    bf16x8 b[4][2];
#pragma unroll
    for (int nt = 0; nt < 4; ++nt)
#pragma unroll
        for (int kk = 0; kk < 2; ++kk)
            b[nt][kk] = __builtin_bit_cast(bf16x8, wpt[(nt * 2 + kk) * 64]);
    __syncthreads();
#pragma unroll
    for (int mi = 0; mi < 4; ++mi) {
        int row = rh * 64 + mi * 16 + (lane & 15);
#pragma unroll
        for (int kk = 0; kk < 2; ++kk) {
            bf16x8 a = __builtin_bit_cast(bf16x8,
                la[row * 8 + (((kk << 2) | (lane >> 4)) ^ (row & 7))]);
#pragma unroll
            for (int nt = 0; nt < 4; ++nt)
                acc[mi][nt] = mfma16(a, b[nt][kk], acc[mi][nt]);
        }
    }
#pragma unroll
    for (int mi = 0; mi < 4; ++mi)
#pragma unroll
        for (int nt = 0; nt < 4; ++nt) {
            int co = nt * 16 + (lane & 15);
#pragma unroll
            for (int r = 0; r < 4; ++r) {
                int node = n0 + rh * 64 + mi * 16 + (lane >> 4) * 4 + r;
                if (side == 0)
                    XLb[node * 64 + co] = __float2bfloat16(acc[mi][nt][r]);
                else
                    XR[node * 64 + co] = acc[mi][nt][r];
            }
        }
}

// ---------------- GAT edge phase ----------------
// block = 32 nodes (4 waves x 8). LDS csr cache kills the csr->gather chain;
// 8 edges per wave-iteration as 2 independent 4-edge batches (2 gathers in flight).
__global__ __launch_bounds__(256) void k_gat(const __hip_bfloat16* __restrict__ XLb,
        const float* __restrict__ XR, const float* __restrict__ att64,
        const float* __restrict__ bias, const int* __restrict__ off,
        const int* __restrict__ csr, __hip_bfloat16* __restrict__ outb) {
    __shared__ int csr_c[320];
    int tid = threadIdx.x;
    int lane = tid & 63;
    int g = lane >> 4;
    int c4 = (lane & 15) << 2;
    int nblk = blockIdx.x * 32;
    int cbase = off[nblk];
    int ccnt = min(off[nblk + 32] - cbase, 320);
    for (int idx = tid; idx < ccnt; idx += 256) csr_c[idx] = csr[cbase + idx];
    __syncthreads();
    const float LOG2E = 1.44269504089f;
    f32x4 a4 = *(const f32x4*)(att64 + c4);
#pragma unroll
    for (int j = 0; j < 4; ++j) a4[j] *= LOG2E;
    f32x4 b4 = *(const f32x4*)(bias + c4);
    int n0 = nblk + ((tid >> 6) << 3);
    for (int n = n0; n < n0 + 8; ++n) {
        int e0 = off[n], e1 = off[n + 1];
        f32x4 xi = *(const f32x4*)(XR + n * 64 + c4);
        float s = 0.f;
        f32x4 acc = (f32x4)0.0f;
        int deg = e1 - e0;
        int rounds = (deg + 7) >> 3;
        int e = e0 + g;
        for (int i = 0; i < rounds; ++i, e += 8) {
            int eA = e, eB = e + 4;
            bool aA = eA < e1, aB = eB < e1;
            int ecA = aA ? eA : e1 - 1;
            int ecB = aB ? eB : e1 - 1;
            int rA = ecA - cbase, rB = ecB - cbase;
            int sA = (rA < ccnt) ? csr_c[rA] : csr[ecA];
            int sB = (rB < ccnt) ? csr_c[rB] : csr[ecB];
            uint2v xwA = *(const uint2v*)(XLb + sA * 64 + c4);
            uint2v xwB = *(const uint2v*)(XLb + sB * 64 + c4);
            f32x4 xjA, xjB;
            unpack4(xwA, xjA);
            unpack4(xwB, xjB);
            float pA = 0.f, pB = 0.f;
#pragma unroll
            for (int j = 0; j < 4; ++j) {
                float vA = xi[j] + xjA[j];
                vA = fmaxf(vA, 0.2f * vA);
                pA = fmaf(vA, a4[j], pA);
                float vB = xi[j] + xjB[j];
                vB = fmaxf(vB, 0.2f * vB);
                pB = fmaf(vB, a4[j], pB);
            }
            pA += __shfl_xor(pA, 1);
            pA += __shfl_xor(pA, 2);
            pB += __shfl_xor(pB, 1);
            pB += __shfl_xor(pB, 2);
            pA = fminf(fmaxf(pA, -60.f), 60.f);
            pB = fminf(fmaxf(pB, -60.f), 60.f);
            float exA = aA ? exp2f(pA) : 0.f;    // shift-invariant softmax
            float exB = aB ? exp2f(pB) : 0.f;
            s += exA + exB;
#pragma unroll
            for (int j = 0; j < 4; ++j) {
                acc[j] = fmaf(exA, xjA[j], acc[j]);
                acc[j] = fmaf(exB, xjB[j], acc[j]);
            }
        }
        s += __shfl_xor(s, 16);
        s += __shfl_xor(s, 32);
#pragma unroll
        for (int j = 0; j < 4; ++j) {
            acc[j] += __shfl_xor(acc[j], 16);
            acc[j] += __shfl_xor(acc[j], 32);
        }
        float inv = 1.f / (s + 1e-16f);
        uint2v o;
        float v0 = acc[0] * inv + b4[0];
        float v1 = acc[1] * inv + b4[1];
        float v2 = acc[2] * inv + b4[2];
        float v3 = acc[3] * inv + b4[3];
        v0 = v0 > 0.f ? v0 : __expf(v0) - 1.f;
        v1 = v1 > 0.f ? v1 : __expf(v1) - 1.f;
        v2 = v2 > 0.f ? v2 : __expf(v2) - 1.f;
        v3 = v3 > 0.f ? v3 : __expf(v3) - 1.f;
        o[0] = (unsigned)f2bs(v0) | ((unsigned)f2bs(v1) << 16);
        o[1] = (unsigned)f2bs(v2) | ((unsigned)f2bs(v3) << 16);
        *(uint2v*)(outb + n * 64 + c4) = o;
    }
}

// ---------------- 1x1 conv (MFMA): out = cat(b0,b1,b2)@W + bias + res ----------------
__global__ __launch_bounds__(256) void k_cc2(const __hip_bfloat16* __restrict__ b0,
        const __hip_bfloat16* __restrict__ b1, const __hip_bfloat16* __restrict__ b2,
        const __hip_bfloat16* __restrict__ pw, const float* __restrict__ bias,
        const float* __restrict__ resin, float* __restrict__ imgout,
        __hip_bfloat16* __restrict__ outb) {
    __shared__ i32x4 la[128 * 8];
    int t = threadIdx.x, lane = t & 63, wid = t >> 6;
    int n0 = blockIdx.x * 128;
    const __hip_bfloat16* brs[3] = {b0, b1, b2};
    const i32x4* wp4 = (const i32x4*)pw;
    f32x4 acc[2][4];
#pragma unroll
    for (int mi = 0; mi < 2; ++mi)
#pragma unroll
        for (int nt = 0; nt < 4; ++nt) acc[mi][nt] = (f32x4)0.0f;
#pragma unroll
    for (int br = 0; br < 3; ++br) {
        __syncthreads();
        const i32x4* Bg = (const i32x4*)brs[br] + n0 * 8;
        for (int idx = t; idx < 1024; idx += 256) {
            int r = idx >> 3, c = idx & 7;
            la[r * 8 + (c ^ (r & 7))] = Bg[idx];
        }
        __syncthreads();
        bf16x8 bf[4][2];
#pragma unroll
        for (int nt = 0; nt < 4; ++nt)
#pragma unroll
            for (int kk = 0; kk < 2; ++kk)
                bf[nt][kk] = __builtin_bit_cast(bf16x8,
                    wp4[(br * 8 + nt * 2 + kk) * 64 + lane]);
#pragma unroll
        for (int mi = 0; mi < 2; ++mi) {
            int row = wid * 32 + mi * 16 + (lane & 15);
#pragma unroll
            for (int kk = 0; kk < 2; ++kk) {
                bf16x8 a = __builtin_bit_cast(bf16x8,
                    la[row * 8 + (((kk << 2) | (lane >> 4)) ^ (row & 7))]);
#pragma unroll
                for (int nt = 0; nt < 4; ++nt)
                    acc[mi][nt] = mfma16(a, bf[nt][kk], acc[mi][nt]);
            }
        }
    }
#pragma unroll
    for (int mi = 0; mi < 2; ++mi)
#pragma unroll
        for (int nt = 0; nt < 4; ++nt) {
            int co = nt * 16 + (lane & 15);
            float bv = bias[co];
#pragma unroll
            for (int r = 0; r < 4; ++r) {
                int node = n0 + wid * 32 + mi * 16 + (lane >> 4) * 4 + r;
                float v = acc[mi][nt][r] + bv + resin[node * 64 + co];
                imgout[node * 64 + co] = v;
                outb[node * 64 + co] = __float2bfloat16(v);
            }
        }
}

// final stage: same GEMM, output NCHW fp32 via LDS transpose
__global__ __launch_bounds__(256) void k_ccfin(const __hip_bfloat16* __restrict__ b0,
        const __hip_bfloat16* __restrict__ b1, const __hip_bfloat16* __restrict__ b2,
        const __hip_bfloat16* __restrict__ pw, const float* __restrict__ bias,
        const float* __restrict__ resin, float* __restrict__ outp) {
    __shared__ i32x4 la[128 * 8];
    __shared__ float tt[64][132];
    int t = threadIdx.x, lane = t & 63, wid = t >> 6;
    int n0 = blockIdx.x * 128;
    const __hip_bfloat16* brs[3] = {b0, b1, b2};
    const i32x4* wp4 = (const i32x4*)pw;
    f32x4 acc[2][4];
#pragma unroll
    for (int mi = 0; mi < 2; ++mi)
#pragma unroll
        for (int nt = 0; nt < 4; ++nt) acc[mi][nt] = (f32x4)0.0f;
#pragma unroll
    for (int br = 0; br < 3; ++br) {
        __syncthreads();
        const i32x4* Bg = (const i32x4*)brs[br] + n0 * 8;
        for (int idx = t; idx < 1024; idx += 256) {
            int r = idx >> 3, c = idx & 7;
            la[r * 8 + (c ^ (r & 7))] = Bg[idx];
        }
        __syncthreads();
        bf16x8 bf[4][2];
#pragma unroll
        for (int nt = 0; nt < 4; ++nt)
#pragma unroll
            for (int kk = 0; kk < 2; ++kk)
                bf[nt][kk] = __builtin_bit_cast(bf16x8,
                    wp4[(br * 8 + nt * 2 + kk) * 64 + lane]);
#pragma unroll
        for (int mi = 0; mi < 2; ++mi) {
            int row = wid * 32 + mi * 16 + (lane & 15);
#pragma unroll
            for (int kk = 0; kk < 2; ++kk) {
                bf16x8 a = __builtin_bit_cast(bf16x8,
                    la[row * 8 + (((kk << 2) | (lane >> 4)) ^ (row & 7))]);
#pragma unroll
                for (int nt = 0; nt < 4; ++nt)
                    acc[mi][nt] = mfma16(a, bf[nt][kk], acc[mi][nt]);
            }
        }
    }
#pragma unroll
    for (int mi = 0; mi < 2; ++mi)
#pragma unroll
        for (int nt = 0; nt < 4; ++nt) {
            int co = nt * 16 + (lane & 15);
            float bv = bias[co];
#pragma unroll
            for (int r = 0; r < 4; ++r) {
                int nl = wid * 32 + mi * 16 + (lane >> 4) * 4 + r;
                tt[co][nl] = acc[mi][nt][r] + bv + resin[(n0 + nl) * 64 + co];
            }
        }
    __syncthreads();
    for (int u = t; u < 2048; u += 256) {
        int row = u >> 5;
        int col = (u & 31) * 4;
        f32x4 v = *(const f32x4*)&tt[row][col];
        *(f32x4*)(outp + row * HW + n0 + col) = v;
    }
}

// ---------------- 3x3 conv 64->64, channels-last, MFMA ----------------
template <int MODE>
__global__ __launch_bounds__(256) void k_conv(const __hip_bfloat16* __restrict__ inb,
        const __hip_bfloat16* __restrict__ wp, const float* __restrict__ bias,
        const float* __restrict__ pa, float* __restrict__ img,
        __hip_bfloat16* __restrict__ outb) {
    __shared__ i32x4 la[130 * 8];
    int t = threadIdx.x, lane = t & 63, wid = t >> 6;
    int y = blockIdx.x >> 1, x0 = (blockIdx.x & 1) << 7;
    f32x4 acc[2][4];
#pragma unroll
    for (int mi = 0; mi < 2; ++mi)
#pragma unroll
        for (int nt = 0; nt < 4; ++nt) acc[mi][nt] = (f32x4)0.0f;
    const i32x4* ing = (const i32x4*)inb;
#pragma unroll
    for (int dy = 0; dy < 3; ++dy) {
        int sy = y + dy - 1;
        bool rowok = (sy >= 0) && (sy < 256);
        __syncthreads();
        for (int idx = t; idx < 1040; idx += 256) {
            int r = idx >> 3, c = idx & 7;
            int sx = x0 - 1 + r;
            i32x4 v = (i32x4)0;
            if (rowok && sx >= 0 && sx < 256) v = ing[(sy * 256 + sx) * 8 + c];
            la[r * 8 + (c ^ (r & 7))] = v;
        }
        __syncthreads();
#pragma unroll
        for (int dx = 0; dx < 3; ++dx) {
            const i32x4* wpt = (const i32x4*)wp + (dy * 3 + dx) * 512 + lane;
            bf16x8 b[4][2];
#pragma unroll
            for (int nt = 0; nt < 4; ++nt)
#pragma unroll
                for (int kk = 0; kk < 2; ++kk)
                    b[nt][kk] = __builtin_bit_cast(bf16x8, wpt[(nt * 2 + kk) * 64]);
#pragma unroll
            for (int mi = 0; mi < 2; ++mi) {
                int row = dx + wid * 32 + mi * 16 + (lane & 15);
#pragma unroll
                for (int kk = 0; kk < 2; ++kk) {
                    bf16x8 a = __builtin_bit_cast(bf16x8,
                        la[row * 8 + (((kk << 2) | (lane >> 4)) ^ (row & 7))]);
#pragma unroll
                    for (int nt = 0; nt < 4; ++nt)
                        acc[mi][nt] = mfma16(a, b[nt][kk], acc[mi][nt]);
                }
            }
        }
    }
    int pbase = y * 256 + x0 + wid * 32 + (lane >> 4) * 4;
    float aprelu = (MODE == 0) ? pa[0] : 0.f;
#pragma unroll
    for (int mi = 0; mi < 2; ++mi)
#pragma unroll
        for (int nt = 0; nt < 4; ++nt) {
            int co = nt * 16 + (lane & 15);
            float bv = bias[co];
#pragma unroll
            for (int r = 0; r < 4; ++r) {
                int pix = pbase + mi * 16 + r;
                float v = acc[mi][nt][r] + bv;
                if (MODE == 0) {
                    v = v >= 0.f ? v : aprelu * v;
                    outb[pix * 64 + co] = __float2bfloat16(v);
                } else {
                    v += img[pix * 64 + co];
                    img[pix * 64 + co] = v;
                    outb[pix * 64 + co] = __float2bfloat16(v);
                }
            }
        }
}

// ---------------- host ----------------
extern "C" void kernel_launch(void* const* d_in, const int* in_sizes, int n_in,
                              void* d_out, int out_size, void* d_ws, size_t ws_size,
                              hipStream_t stream) {
    const float* x    = (const float*)d_in[0];
    const int*   ei   = (const int*)d_in[1];
    const float* gWl  = (const float*)d_in[2];   // [27][64][64]
    const float* gWr  = (const float*)d_in[3];
    const float* gatt = (const float*)d_in[4];   // [27][64]
    const float* gb   = (const float*)d_in[5];   // [27][64]
    const float* ccw  = (const float*)d_in[6];   // [3][64][192]
    const float* ccb  = (const float*)d_in[7];   // [3][64]
    const float* rbw  = (const float*)d_in[8];   // [16][64][64][3][3]
    const float* rbb  = (const float*)d_in[9];   // [16][64]
    const float* rba  = (const float*)d_in[10];  // [8]
    float* outp = (float*)d_out;

    float* wsf = (float*)d_ws;
    float* xn  = wsf;            // [N,64] fp32 stage-0 residual
    float* xr  = xn  + NC;
    float* img = xr  + NC;       // [N,64] fp32 running image
    __hip_bfloat16* xlb  = (__hip_bfloat16*)(img + NC);
    __hip_bfloat16* xb   = xlb + NC;
    __hip_bfloat16* t0b  = xb  + NC;
    __hip_bfloat16* cvb  = t0b + NC;
    __hip_bfloat16* b0b  = cvb + NC;
    __hip_bfloat16* b1b  = b0b + NC;
    __hip_bfloat16* b2b  = b1b + NC;
    __hip_bfloat16* wpkc = b2b + NC;        // 589824
    __hip_bfloat16* wpkm = wpkc + 589824;   // 221184
    __hip_bfloat16* ccpk = wpkm + 221184;   // 36864
    int* ioff = (int*)(ccpk + 36864);
    int* icnt = ioff + (N_NODES + 1);
    int* icur = icnt + N_NODES;
    int* icsr = icur + N_NODES;             // NE

    const int* srcA = ei;
    const int* dstA = ei + NE;

    hipMemsetAsync(icnt, 0, N_NODES * sizeof(int), stream);
    k_hist<<<NE / 256, 256, 0, stream>>>(dstA, icnt);
    k_scan<<<1, 1024, 0, stream>>>(icnt, ioff);
    hipMemcpyAsync(icur, ioff, N_NODES * sizeof(int), hipMemcpyDeviceToDevice, stream);
    k_fill<<<NE / 256, 256, 0, stream>>>(srcA, dstA, icur, icsr);
    k_cvpack<<<2304, 256, 0, stream>>>(rbw, wpkc);
    k_mmpack<<<864, 256, 0, stream>>>(gWl, gWr, wpkm);
    k_ccpack<<<144, 256, 0, stream>>>(ccw, ccpk);
    k_init<<<1024, 256, 0, stream>>>(x, xn, xb);

    __hip_bfloat16* brsb[3] = {b0b, b1b, b2b};
    for (int st = 0; st < 3; ++st) {
        for (int mb = 0; mb < 3; ++mb) {
            const __hip_bfloat16* lin = xb;
            for (int l = 0; l < 3; ++l) {
                int lay = (st * 3 + mb) * 3 + l;
                k_mm<<<N_NODES / 128, 256, 0, stream>>>(lin, wpkm + lay * 8192, xlb, xr);
                const float* at = gatt + lay * 64;
                const float* bb = gb + lay * 64;
                __hip_bfloat16* dst = (l < 2) ? t0b : brsb[mb];
                k_gat<<<2048, 256, 0, stream>>>(xlb, xr, at, bb, ioff, icsr, dst);
                lin = t0b;
            }
        }
        const float* resin = (st == 0) ? xn : img;
        if (st == 2) {
            k_ccfin<<<N_NODES / 128, 256, 0, stream>>>(b0b, b1b, b2b,
                ccpk + 2 * 12288, ccb + 128, resin, outp);
        } else {
            k_cc2<<<N_NODES / 128, 256, 0, stream>>>(b0b, b1b, b2b,
                ccpk + st * 12288, ccb + st * 64, resin, img, xb);
            for (int bk = 0; bk < 4; ++bk) {
                int cv = (st * 4 + bk) * 2;
                k_conv<0><<<512, 256, 0, stream>>>(xb, wpkc + (size_t)cv * 36864,
                    rbb + cv * 64, rba + st * 4 + bk, nullptr, cvb);
                k_conv<1><<<512, 256, 0, stream>>>(cvb, wpkc + (size_t)(cv + 1) * 36864,
                    rbb + (cv + 1) * 64, nullptr, img, xb);
            }
        }
    }
}

// Round 6
// 1334.724 us; speedup vs baseline: 5.5062x; 1.1378x over previous
//
#include <hip/hip_runtime.h>
#include <hip/hip_bf16.h>
#include <math.h>

#define N_NODES 65536
#define HW      65536
#define NE      524288
#define NC      (N_NODES * 64)

typedef __bf16 bf16x8 __attribute__((ext_vector_type(8)));
typedef float  f32x4  __attribute__((ext_vector_type(4)));
typedef int    i32x4  __attribute__((ext_vector_type(4)));
typedef unsigned int uint2v __attribute__((ext_vector_type(2)));

static __device__ __forceinline__ f32x4 mfma16(bf16x8 a, bf16x8 b, f32x4 c) {
    return __builtin_amdgcn_mfma_f32_16x16x32_bf16(a, b, c, 0, 0, 0);
}

static __device__ __forceinline__ unsigned short f2bs(float f) {
    return __builtin_bit_cast(unsigned short, __float2bfloat16(f));
}

static __device__ __forceinline__ void unpack4(uint2v xw, f32x4& xj) {
    xj[0] = __builtin_bit_cast(float, xw[0] << 16);
    xj[1] = __builtin_bit_cast(float, xw[0] & 0xffff0000u);
    xj[2] = __builtin_bit_cast(float, xw[1] << 16);
    xj[3] = __builtin_bit_cast(float, xw[1] & 0xffff0000u);
}

// ---------------- CSR build ----------------
__global__ void k_hist(const int* __restrict__ dstA, int* __restrict__ cnt) {
    int e = blockIdx.x * 256 + threadIdx.x;
    if (e < NE) atomicAdd(&cnt[dstA[e]], 1);
}

__global__ void k_scan(const int* __restrict__ cnt, int* __restrict__ off) {
    __shared__ int sums[1024];
    int t = threadIdx.x;
    int base = t * 64;
    int s = 0;
    for (int i = 0; i < 64; ++i) s += cnt[base + i];
    sums[t] = s;
    __syncthreads();
    for (int d = 1; d < 1024; d <<= 1) {
        int v = (t >= d) ? sums[t - d] : 0;
        __syncthreads();
        sums[t] += v;
        __syncthreads();
    }
    int run = sums[t] - s;  // exclusive prefix
    for (int i = 0; i < 64; ++i) { off[base + i] = run; run += cnt[base + i]; }
    if (t == 1023) off[N_NODES] = run;
}

__global__ void k_fill(const int* __restrict__ srcA, const int* __restrict__ dstA,
                       int* __restrict__ cur, int* __restrict__ csr) {
    int e = blockIdx.x * 256 + threadIdx.x;
    if (e < NE) {
        int p = atomicAdd(&cur[dstA[e]], 1);
        csr[p] = srcA[e];
    }
}

// ---------------- weight packing (MFMA fragment order) ----------------
// conv: rb_w [16][co][ci][3][3] -> [cv][tap][nt][kk][lane][8] bf16
__global__ void k_cvpack(const float* __restrict__ w, __hip_bfloat16* __restrict__ d) {
    int idx = blockIdx.x * 256 + threadIdx.x;
    if (idx >= 589824) return;
    int j = idx & 7, lane = (idx >> 3) & 63, r = idx >> 9;
    int kk = r & 1; r >>= 1;
    int nt = r & 3; r >>= 2;
    int tap = r % 9, cv = r / 9;
    int co = nt * 16 + (lane & 15);
    int ci = kk * 32 + (lane >> 4) * 8 + j;
    d[idx] = __float2bfloat16(w[((cv * 64 + co) * 64 + ci) * 9 + tap]);
}

// gat mm: gWl/gWr [27][ci][co] -> [lay][side][nt][kk][lane][8] bf16
__global__ void k_mmpack(const float* __restrict__ Wl, const float* __restrict__ Wr,
                         __hip_bfloat16* __restrict__ d) {
    int idx = blockIdx.x * 256 + threadIdx.x;
    if (idx >= 221184) return;
    int j = idx & 7, lane = (idx >> 3) & 63, r = idx >> 9;
    int kk = r & 1; r >>= 1;
    int nt = r & 3; r >>= 2;
    int side = r & 1, lay = r >> 1;
    int co = nt * 16 + (lane & 15);
    int ci = kk * 32 + (lane >> 4) * 8 + j;
    const float* W = side ? Wr : Wl;
    d[idx] = __float2bfloat16(W[lay * 4096 + ci * 64 + co]);
}

// cc_w [3][o=64][k=192] -> [st][br][nt][kk][lane][8] bf16
__global__ void k_ccpack(const float* __restrict__ w, __hip_bfloat16* __restrict__ d) {
    int idx = blockIdx.x * 256 + threadIdx.x;
    if (idx >= 36864) return;
    int j = idx & 7;
    int u = idx >> 3;
    int lane = u & 63;
    int f = (u >> 6) & 7;
    int sb = u >> 9;
    int kk = f & 1, nt = f >> 1;
    int br = sb % 3, st = sb / 3;
    int k = br * 64 + kk * 32 + (lane >> 4) * 8 + j;
    int co = nt * 16 + (lane & 15);
    d[idx] = __float2bfloat16(w[st * 12288 + co * 192 + k]);
}

// ---------------- initial NCHW -> [N,64] fp32 + bf16 ----------------
__global__ void k_init(const float* __restrict__ img, float* __restrict__ xn,
                       __hip_bfloat16* __restrict__ xb) {
    __shared__ float tile[64][65];
    int nb = blockIdx.x * 64;
    for (int idx = threadIdx.x; idx < 4096; idx += 256) {
        int c = idx >> 6, n = idx & 63;
        tile[c][n] = img[c * HW + nb + n];
    }
    __syncthreads();
    for (int idx = threadIdx.x; idx < 4096; idx += 256) {
        int n = idx >> 6, c = idx & 63;
        float v = tile[c][n];
        xn[(nb + n) * 64 + c] = v;
        xb[(nb + n) * 64 + c] = __float2bfloat16(v);
    }
}

// ---------------- MFMA dual matmul: XLb = bf16(X@Wl), XRb = bf16(X@Wr) ----------------
__global__ __launch_bounds__(256) void k_mm(const __hip_bfloat16* __restrict__ Xb,
        const __hip_bfloat16* __restrict__ pw, __hip_bfloat16* __restrict__ XLb,
        __hip_bfloat16* __restrict__ XRb) {
    __shared__ i32x4 la[128 * 8];
    int t = threadIdx.x, lane = t & 63, wid = t >> 6;
    int n0 = blockIdx.x * 128;
    const i32x4* Xg = (const i32x4*)Xb + n0 * 8;
    for (int idx = t; idx < 1024; idx += 256) {
        int r = idx >> 3, c = idx & 7;
        la[r * 8 + (c ^ (r & 7))] = Xg[idx];
    }
    int side = wid & 1, rh = wid >> 1;
    const i32x4* wpt = (const i32x4*)pw + side * 512 + lane;
    f32x4 acc[4][4];
#pragma unroll
    for (int mi = 0; mi < 4; ++mi)
#pragma unroll
        for (int nt = 0; nt < 4; ++nt) acc[mi][nt] = (f32x4)0.0f;
    bf16x8 b[4][2];
#pragma unroll
    for (int nt = 0; nt < 4; ++nt)
#pragma unroll
        for (int kk = 0; kk < 2; ++kk)
            b[nt][kk] = __builtin_bit_cast(bf16x8, wpt[(nt * 2 + kk) * 64]);
    __syncthreads();
#pragma unroll
    for (int mi = 0; mi < 4; ++mi) {
        int row = rh * 64 + mi * 16 + (lane & 15);
#pragma unroll
        for (int kk = 0; kk < 2; ++kk) {
            bf16x8 a = __builtin_bit_cast(bf16x8,
                la[row * 8 + (((kk << 2) | (lane >> 4)) ^ (row & 7))]);
#pragma unroll
            for (int nt = 0; nt < 4; ++nt)
                acc[mi][nt] = mfma16(a, b[nt][kk], acc[mi][nt]);
        }
    }
    __hip_bfloat16* O = side ? XRb : XLb;
#pragma unroll
    for (int mi = 0; mi < 4; ++mi)
#pragma unroll
        for (int nt = 0; nt < 4; ++nt) {
            int co = nt * 16 + (lane & 15);
#pragma unroll
            for (int r = 0; r < 4; ++r) {
                int node = n0 + rh * 64 + mi * 16 + (lane >> 4) * 4 + r;
                O[node * 64 + co] = __float2bfloat16(acc[mi][nt][r]);
            }
        }
}

// ---------------- GAT edge phase ----------------
// 16-lane group OWNS one node (4 ch/lane covers all 64 ch). Softmax is per-head
// (16 ch = one quad), so the logit reduce is quad-only (xor 1,2) and the per-lane
// s/acc are already complete per head -> NO cross-lane epilogue reduction at all.
// 2 edges per group per round (2 gathers in flight). Block = 32 nodes, LDS csr cache.
__global__ __launch_bounds__(256) void k_gat(const __hip_bfloat16* __restrict__ XLb,
        const __hip_bfloat16* __restrict__ XRb, const float* __restrict__ att64,
        const float* __restrict__ bias, const int* __restrict__ off,
        const int* __restrict__ csr, __hip_bfloat16* __restrict__ outb) {
    __shared__ int csr_c[320];
    int tid = threadIdx.x;
    int lane = tid & 63;
    int g = (lane >> 4) & 3;
    int c4 = (lane & 15) << 2;
    int nblk = blockIdx.x * 32;
    int cbase = off[nblk];
    int ccnt = min(off[nblk + 32] - cbase, 320);
    for (int idx = tid; idx < ccnt; idx += 256) csr_c[idx] = csr[cbase + idx];
    __syncthreads();
    const float LOG2E = 1.44269504089f;
    f32x4 a4 = *(const f32x4*)(att64 + c4);
#pragma unroll
    for (int j = 0; j < 4; ++j) a4[j] *= LOG2E;
    f32x4 b4 = *(const f32x4*)(bias + c4);
    int base = nblk + ((tid >> 6) << 3) + g * 2;   // 2 consecutive nodes per group
#pragma unroll
    for (int nn = 0; nn < 2; ++nn) {
        int n = base + nn;
        int e0 = off[n], e1 = off[n + 1];
        uint2v xw = *(const uint2v*)(XRb + n * 64 + c4);
        f32x4 xi;
        unpack4(xw, xi);
        float s = 0.f;
        f32x4 acc = (f32x4)0.0f;
        int rounds = (e1 - e0 + 1) >> 1;
        int e = e0;
        for (int i = 0; i < rounds; ++i, e += 2) {
            bool aB = (e + 1) < e1;
            int eB = aB ? e + 1 : e;
            int rA = e - cbase, rB = eB - cbase;
            int sA = (rA < ccnt) ? csr_c[rA] : csr[e];
            int sB = (rB < ccnt) ? csr_c[rB] : csr[eB];
            uint2v wA = *(const uint2v*)(XLb + sA * 64 + c4);
            uint2v wB = *(const uint2v*)(XLb + sB * 64 + c4);
            f32x4 xjA, xjB;
            unpack4(wA, xjA);
            unpack4(wB, xjB);
            float pA = 0.f, pB = 0.f;
#pragma unroll
            for (int j = 0; j < 4; ++j) {
                float vA = xi[j] + xjA[j];
                vA = fmaxf(vA, 0.2f * vA);       // leaky_relu(0.2)
                pA = fmaf(vA, a4[j], pA);
                float vB = xi[j] + xjB[j];
                vB = fmaxf(vB, 0.2f * vB);
                pB = fmaf(vB, a4[j], pB);
            }
            pA += __shfl_xor(pA, 1);
            pA += __shfl_xor(pA, 2);             // per-head logit (quad reduce)
            pB += __shfl_xor(pB, 1);
            pB += __shfl_xor(pB, 2);
            float exA = exp2f(fmaxf(pA, -100.f));    // shift-invariant softmax
            float exB = exp2f(fmaxf(pB, -100.f));
            exB = aB ? exB : 0.f;
            s += exA + exB;
#pragma unroll
            for (int j = 0; j < 4; ++j)
                acc[j] = fmaf(exA, xjA[j], fmaf(exB, xjB[j], acc[j]));
        }
        float inv = __builtin_amdgcn_rcpf(s + 1e-16f);
        float v0 = fmaf(acc[0], inv, b4[0]);
        float v1 = fmaf(acc[1], inv, b4[1]);
        float v2 = fmaf(acc[2], inv, b4[2]);
        float v3 = fmaf(acc[3], inv, b4[3]);
        v0 = v0 > 0.f ? v0 : __expf(v0) - 1.f;   // ELU
        v1 = v1 > 0.f ? v1 : __expf(v1) - 1.f;
        v2 = v2 > 0.f ? v2 : __expf(v2) - 1.f;
        v3 = v3 > 0.f ? v3 : __expf(v3) - 1.f;
        uint2v o;
        o[0] = (unsigned)f2bs(v0) | ((unsigned)f2bs(v1) << 16);
        o[1] = (unsigned)f2bs(v2) | ((unsigned)f2bs(v3) << 16);
        *(uint2v*)(outb + n * 64 + c4) = o;
    }
}

// ---------------- 1x1 conv (MFMA): out = cat(b0,b1,b2)@W + bias + res ----------------
__global__ __launch_bounds__(256) void k_cc2(const __hip_bfloat16* __restrict__ b0,
        const __hip_bfloat16* __restrict__ b1, const __hip_bfloat16* __restrict__ b2,
        const __hip_bfloat16* __restrict__ pw, const float* __restrict__ bias,
        const float* __restrict__ resin, float* __restrict__ imgout,
        __hip_bfloat16* __restrict__ outb) {
    __shared__ i32x4 la[128 * 8];
    int t = threadIdx.x, lane = t & 63, wid = t >> 6;
    int n0 = blockIdx.x * 128;
    const __hip_bfloat16* brs[3] = {b0, b1, b2};
    const i32x4* wp4 = (const i32x4*)pw;
    f32x4 acc[2][4];
#pragma unroll
    for (int mi = 0; mi < 2; ++mi)
#pragma unroll
        for (int nt = 0; nt < 4; ++nt) acc[mi][nt] = (f32x4)0.0f;
#pragma unroll
    for (int br = 0; br < 3; ++br) {
        __syncthreads();
        const i32x4* Bg = (const i32x4*)brs[br] + n0 * 8;
        for (int idx = t; idx < 1024; idx += 256) {
            int r = idx >> 3, c = idx & 7;
            la[r * 8 + (c ^ (r & 7))] = Bg[idx];
        }
        __syncthreads();
        bf16x8 bf[4][2];
#pragma unroll
        for (int nt = 0; nt < 4; ++nt)
#pragma unroll
            for (int kk = 0; kk < 2; ++kk)
                bf[nt][kk] = __builtin_bit_cast(bf16x8,
                    wp4[(br * 8 + nt * 2 + kk) * 64 + lane]);
#pragma unroll
        for (int mi = 0; mi < 2; ++mi) {
            int row = wid * 32 + mi * 16 + (lane & 15);
#pragma unroll
            for (int kk = 0; kk < 2; ++kk) {
                bf16x8 a = __builtin_bit_cast(bf16x8,
                    la[row * 8 + (((kk << 2) | (lane >> 4)) ^ (row & 7))]);
#pragma unroll
                for (int nt = 0; nt < 4; ++nt)
                    acc[mi][nt] = mfma16(a, bf[nt][kk], acc[mi][nt]);
            }
        }
    }
#pragma unroll
    for (int mi = 0; mi < 2; ++mi)
#pragma unroll
        for (int nt = 0; nt < 4; ++nt) {
            int co = nt * 16 + (lane & 15);
            float bv = bias[co];
#pragma unroll
            for (int r = 0; r < 4; ++r) {
                int node = n0 + wid * 32 + mi * 16 + (lane >> 4) * 4 + r;
                float v = acc[mi][nt][r] + bv + resin[node * 64 + co];
                imgout[node * 64 + co] = v;
                outb[node * 64 + co] = __float2bfloat16(v);
            }
        }
}

// final stage: same GEMM, output NCHW fp32 via LDS transpose
__global__ __launch_bounds__(256) void k_ccfin(const __hip_bfloat16* __restrict__ b0,
        const __hip_bfloat16* __restrict__ b1, const __hip_bfloat16* __restrict__ b2,
        const __hip_bfloat16* __restrict__ pw, const float* __restrict__ bias,
        const float* __restrict__ resin, float* __restrict__ outp) {
    __shared__ i32x4 la[128 * 8];
    __shared__ float tt[64][132];
    int t = threadIdx.x, lane = t & 63, wid = t >> 6;
    int n0 = blockIdx.x * 128;
    const __hip_bfloat16* brs[3] = {b0, b1, b2};
    const i32x4* wp4 = (const i32x4*)pw;
    f32x4 acc[2][4];
#pragma unroll
    for (int mi = 0; mi < 2; ++mi)
#pragma unroll
        for (int nt = 0; nt < 4; ++nt) acc[mi][nt] = (f32x4)0.0f;
#pragma unroll
    for (int br = 0; br < 3; ++br) {
        __syncthreads();
        const i32x4* Bg = (const i32x4*)brs[br] + n0 * 8;
        for (int idx = t; idx < 1024; idx += 256) {
            int r = idx >> 3, c = idx & 7;
            la[r * 8 + (c ^ (r & 7))] = Bg[idx];
        }
        __syncthreads();
        bf16x8 bf[4][2];
#pragma unroll
        for (int nt = 0; nt < 4; ++nt)
#pragma unroll
            for (int kk = 0; kk < 2; ++kk)
                bf[nt][kk] = __builtin_bit_cast(bf16x8,
                    wp4[(br * 8 + nt * 2 + kk) * 64 + lane]);
#pragma unroll
        for (int mi = 0; mi < 2; ++mi) {
            int row = wid * 32 + mi * 16 + (lane & 15);
#pragma unroll
            for (int kk = 0; kk < 2; ++kk) {
                bf16x8 a = __builtin_bit_cast(bf16x8,
                    la[row * 8 + (((kk << 2) | (lane >> 4)) ^ (row & 7))]);
#pragma unroll
                for (int nt = 0; nt < 4; ++nt)
                    acc[mi][nt] = mfma16(a, bf[nt][kk], acc[mi][nt]);
            }
        }
    }
#pragma unroll
    for (int mi = 0; mi < 2; ++mi)
#pragma unroll
        for (int nt = 0; nt < 4; ++nt) {
            int co = nt * 16 + (lane & 15);
            float bv = bias[co];
#pragma unroll
            for (int r = 0; r < 4; ++r) {
                int nl = wid * 32 + mi * 16 + (lane >> 4) * 4 + r;
                tt[co][nl] = acc[mi][nt][r] + bv + resin[(n0 + nl) * 64 + co];
            }
        }
    __syncthreads();
    for (int u = t; u < 2048; u += 256) {
        int row = u >> 5;
        int col = (u & 31) * 4;
        f32x4 v = *(const f32x4*)&tt[row][col];
        *(f32x4*)(outp + row * HW + n0 + col) = v;
    }
}

// ---------------- 3x3 conv 64->64, channels-last, MFMA ----------------
template <int MODE>
__global__ __launch_bounds__(256) void k_conv(const __hip_bfloat16* __restrict__ inb,
        const __hip_bfloat16* __restrict__ wp, const float* __restrict__ bias,
        const float* __restrict__ pa, float* __restrict__ img,
        __hip_bfloat16* __restrict__ outb) {
    __shared__ i32x4 la[130 * 8];
    int t = threadIdx.x, lane = t & 63, wid = t >> 6;
    int y = blockIdx.x >> 1, x0 = (blockIdx.x & 1) << 7;
    f32x4 acc[2][4];
#pragma unroll
    for (int mi = 0; mi < 2; ++mi)
#pragma unroll
        for (int nt = 0; nt < 4; ++nt) acc[mi][nt] = (f32x4)0.0f;
    const i32x4* ing = (const i32x4*)inb;
#pragma unroll
    for (int dy = 0; dy < 3; ++dy) {
        int sy = y + dy - 1;
        bool rowok = (sy >= 0) && (sy < 256);
        __syncthreads();
        for (int idx = t; idx < 1040; idx += 256) {
            int r = idx >> 3, c = idx & 7;
            int sx = x0 - 1 + r;
            i32x4 v = (i32x4)0;
            if (rowok && sx >= 0 && sx < 256) v = ing[(sy * 256 + sx) * 8 + c];
            la[r * 8 + (c ^ (r & 7))] = v;
        }
        __syncthreads();
#pragma unroll
        for (int dx = 0; dx < 3; ++dx) {
            const i32x4* wpt = (const i32x4*)wp + (dy * 3 + dx) * 512 + lane;
            bf16x8 b[4][2];
#pragma unroll
            for (int nt = 0; nt < 4; ++nt)
#pragma unroll
                for (int kk = 0; kk < 2; ++kk)
                    b[nt][kk] = __builtin_bit_cast(bf16x8, wpt[(nt * 2 + kk) * 64]);
#pragma unroll
            for (int mi = 0; mi < 2; ++mi) {
                int row = dx + wid * 32 + mi * 16 + (lane & 15);
#pragma unroll
                for (int kk = 0; kk < 2; ++kk) {
                    bf16x8 a = __builtin_bit_cast(bf16x8,
                        la[row * 8 + (((kk << 2) | (lane >> 4)) ^ (row & 7))]);
#pragma unroll
                    for (int nt = 0; nt < 4; ++nt)
                        acc[mi][nt] = mfma16(a, b[nt][kk], acc[mi][nt]);
                }
            }
        }
    }
    int pbase = y * 256 + x0 + wid * 32 + (lane >> 4) * 4;
    float aprelu = (MODE == 0) ? pa[0] : 0.f;
#pragma unroll
    for (int mi = 0; mi < 2; ++mi)
#pragma unroll
        for (int nt = 0; nt < 4; ++nt) {
            int co = nt * 16 + (lane & 15);
            float bv = bias[co];
#pragma unroll
            for (int r = 0; r < 4; ++r) {
                int pix = pbase + mi * 16 + r;
                float v = acc[mi][nt][r] + bv;
                if (MODE == 0) {
                    v = v >= 0.f ? v : aprelu * v;
                    outb[pix * 64 + co] = __float2bfloat16(v);
                } else {
                    v += img[pix * 64 + co];
                    img[pix * 64 + co] = v;
                    outb[pix * 64 + co] = __float2bfloat16(v);
                }
            }
        }
}

// ---------------- host ----------------
extern "C" void kernel_launch(void* const* d_in, const int* in_sizes, int n_in,
                              void* d_out, int out_size, void* d_ws, size_t ws_size,
                              hipStream_t stream) {
    const float* x    = (const float*)d_in[0];
    const int*   ei   = (const int*)d_in[1];
    const float* gWl  = (const float*)d_in[2];   // [27][64][64]
    const float* gWr  = (const float*)d_in[3];
    const float* gatt = (const float*)d_in[4];   // [27][64]
    const float* gb   = (const float*)d_in[5];   // [27][64]
    const float* ccw  = (const float*)d_in[6];   // [3][64][192]
    const float* ccb  = (const float*)d_in[7];   // [3][64]
    const float* rbw  = (const float*)d_in[8];   // [16][64][64][3][3]
    const float* rbb  = (const float*)d_in[9];   // [16][64]
    const float* rba  = (const float*)d_in[10];  // [8]
    float* outp = (float*)d_out;

    float* wsf = (float*)d_ws;
    float* xn  = wsf;            // [N,64] fp32 stage-0 residual
    float* xrs = xn  + NC;       // slot reused as bf16 XRb
    float* img = xrs + NC;       // [N,64] fp32 running image
    __hip_bfloat16* xrb  = (__hip_bfloat16*)xrs;
    __hip_bfloat16* xlb  = (__hip_bfloat16*)(img + NC);
    __hip_bfloat16* xb   = xlb + NC;
    __hip_bfloat16* t0b  = xb  + NC;
    __hip_bfloat16* cvb  = t0b + NC;
    __hip_bfloat16* b0b  = cvb + NC;
    __hip_bfloat16* b1b  = b0b + NC;
    __hip_bfloat16* b2b  = b1b + NC;
    __hip_bfloat16* wpkc = b2b + NC;        // 589824
    __hip_bfloat16* wpkm = wpkc + 589824;   // 221184
    __hip_bfloat16* ccpk = wpkm + 221184;   // 36864
    int* ioff = (int*)(ccpk + 36864);
    int* icnt = ioff + (N_NODES + 1);
    int* icur = icnt + N_NODES;
    int* icsr = icur + N_NODES;             // NE

    const int* srcA = ei;
    const int* dstA = ei + NE;

    hipMemsetAsync(icnt, 0, N_NODES * sizeof(int), stream);
    k_hist<<<NE / 256, 256, 0, stream>>>(dstA, icnt);
    k_scan<<<1, 1024, 0, stream>>>(icnt, ioff);
    hipMemcpyAsync(icur, ioff, N_NODES * sizeof(int), hipMemcpyDeviceToDevice, stream);
    k_fill<<<NE / 256, 256, 0, stream>>>(srcA, dstA, icur, icsr);
    k_cvpack<<<2304, 256, 0, stream>>>(rbw, wpkc);
    k_mmpack<<<864, 256, 0, stream>>>(gWl, gWr, wpkm);
    k_ccpack<<<144, 256, 0, stream>>>(ccw, ccpk);
    k_init<<<1024, 256, 0, stream>>>(x, xn, xb);

    __hip_bfloat16* brsb[3] = {b0b, b1b, b2b};
    for (int st = 0; st < 3; ++st) {
        for (int mb = 0; mb < 3; ++mb) {
            const __hip_bfloat16* lin = xb;
            for (int l = 0; l < 3; ++l) {
                int lay = (st * 3 + mb) * 3 + l;
                k_mm<<<N_NODES / 128, 256, 0, stream>>>(lin, wpkm + lay * 8192, xlb, xrb);
                const float* at = gatt + lay * 64;
                const float* bb = gb + lay * 64;
                __hip_bfloat16* dst = (l < 2) ? t0b : brsb[mb];
                k_gat<<<2048, 256, 0, stream>>>(xlb, xrb, at, bb, ioff, icsr, dst);
                lin = t0b;
            }
        }
        const float* resin = (st == 0) ? xn : img;
        if (st == 2) {
            k_ccfin<<<N_NODES / 128, 256, 0, stream>>>(b0b, b1b, b2b,
                ccpk + 2 * 12288, ccb + 128, resin, outp);
        } else {
            k_cc2<<<N_NODES / 128, 256, 0, stream>>>(b0b, b1b, b2b,
                ccpk + st * 12288, ccb + st * 64, resin, img, xb);
            for (int bk = 0; bk < 4; ++bk) {
                int cv = (st * 4 + bk) * 2;
                k_conv<0><<<512, 256, 0, stream>>>(xb, wpkc + (size_t)cv * 36864,
                    rbb + cv * 64, rba + st * 4 + bk, nullptr, cvb);
                k_conv<1><<<512, 256, 0, stream>>>(cvb, wpkc + (size_t)(cv + 1) * 36864,
                    rbb + (cv + 1) * 64, nullptr, img, xb);
            }
        }
    }
}